// Round 1
// baseline (4333.202 us; speedup 1.0000x reference)
//
#include <hip/hip_runtime.h>
#include <cmath>

#define BB   8192     // batch rows
#define NEc  8192     // number of codes
#define KD   1024     // full dim
#define DH   512      // half dim
#define NJ   128      // NEc / 64 column tiles

// ---------------- workspace layout (units: floats) ----------------
#define WS_ZN    ((size_t)0)
#define WS_EN    (WS_ZN + (size_t)BB*KD)            // 8388608
#define WS_Z2T   (WS_EN + (size_t)NEc*KD)
#define WS_Z2G   (WS_Z2T + BB)
#define WS_E2T   (WS_Z2G + BB)
#define WS_E2G   (WS_E2T + NEc)
#define NPART    ((size_t)BB*NJ)                    // 1048576
#define WS_PM    (WS_E2G + NEc)
#define WS_PZ    (WS_PM + NPART)
#define WS_PS1   (WS_PZ + NPART)
#define WS_PDMIN (WS_PS1 + NPART)
#define WS_PDT2  (WS_PDMIN + NPART)
#define WS_PDG2  (WS_PDT2 + NPART)
#define WS_PIDX  (WS_PDG2 + NPART)                  // int
#define WS_LSE   (WS_PIDX + NPART)
#define WS_IDX   (WS_LSE + BB)                      // int
#define WS_AVGP  (WS_IDX + BB)
#define WS_SCAL  (WS_AVGP + NEc)
#define WS_BASE_END (WS_SCAL + 16)
#define WS_LMAT  WS_BASE_END
#define WS_STORE_END (WS_LMAT + (size_t)BB*NEc)

// ---------------- output layout (floats) ----------------
#define O_ZQ  ((size_t)0)
#define O_VQ  ((size_t)8388608)
#define O_CM  ((size_t)8388609)
#define O_ENT ((size_t)8388610)
#define O_TD  ((size_t)8388611)
#define O_GD  ((size_t)8388612)
#define O_ZT  ((size_t)8388613)
#define O_ZG  (O_ZT + (size_t)BB*DH)
#define O_IX  (O_ZG + (size_t)BB*DH)

__global__ __launch_bounds__(256) void k_zero(float* __restrict__ p, int n) {
    int i = blockIdx.x * 256 + threadIdx.x;
    if (i < n) p[i] = 0.0f;
}

// normalize z rows: halves [0,512) and [512,1024) independently
__global__ __launch_bounds__(256) void k_norm_z(const float* __restrict__ z, float* __restrict__ zn,
                                                float* __restrict__ z2t, float* __restrict__ z2g) {
    int b = blockIdx.x, t = threadIdx.x;
    const float4 v = *(const float4*)(z + (size_t)b * KD + (size_t)t * 4);
    __shared__ float red[256];
    red[t] = v.x*v.x + v.y*v.y + v.z*v.z + v.w*v.w;
    __syncthreads();
    for (int s = 64; s > 0; s >>= 1) { if ((t & 127) < s) red[t] += red[t + s]; __syncthreads(); }
    float nrm = sqrtf(red[(t < 128) ? 0 : 128]);
    float4 nv;
    nv.x = v.x / nrm; nv.y = v.y / nrm; nv.z = v.z / nrm; nv.w = v.w / nrm;
    *(float4*)(zn + (size_t)b * KD + (size_t)t * 4) = nv;
    __syncthreads();
    red[t] = nv.x*nv.x + nv.y*nv.y + nv.z*nv.z + nv.w*nv.w;
    __syncthreads();
    for (int s = 64; s > 0; s >>= 1) { if ((t & 127) < s) red[t] += red[t + s]; __syncthreads(); }
    if (t == 0)   z2t[b] = red[0];
    if (t == 128) z2g[b] = red[128];
}

// normalize emb rows: threads [0,128) handle emb_text row, [128,256) emb_graph row
__global__ __launch_bounds__(256) void k_norm_e(const float* __restrict__ et, const float* __restrict__ eg,
                                                float* __restrict__ en, float* __restrict__ e2t,
                                                float* __restrict__ e2g) {
    int r = blockIdx.x, t = threadIdx.x;
    const float* src = (t < 128) ? (et + (size_t)r * DH + (size_t)t * 4)
                                 : (eg + (size_t)r * DH + (size_t)(t - 128) * 4);
    const float4 v = *(const float4*)src;
    __shared__ float red[256];
    red[t] = v.x*v.x + v.y*v.y + v.z*v.z + v.w*v.w;
    __syncthreads();
    for (int s = 64; s > 0; s >>= 1) { if ((t & 127) < s) red[t] += red[t + s]; __syncthreads(); }
    float nrm = sqrtf(red[(t < 128) ? 0 : 128]);
    float4 nv;
    nv.x = v.x / nrm; nv.y = v.y / nrm; nv.z = v.z / nrm; nv.w = v.w / nrm;
    float* dst = en + (size_t)r * KD + ((t < 128) ? (size_t)t * 4 : (size_t)DH + (size_t)(t - 128) * 4);
    *(float4*)dst = nv;
    __syncthreads();
    red[t] = nv.x*nv.x + nv.y*nv.y + nv.z*nv.z + nv.w*nv.w;
    __syncthreads();
    for (int s = 64; s > 0; s >>= 1) { if ((t & 127) < s) red[t] += red[t + s]; __syncthreads(); }
    if (t == 0)   e2t[r] = red[0];
    if (t == 128) e2g[r] = red[128];
}

#define GEMM_STEP(ACC) \
    _Pragma("unroll") \
    for (int kk = 0; kk < 16; ++kk) { \
        const float4 a4 = *(const float4*)&As[kk][ty * 4]; \
        const float4 b4 = *(const float4*)&Bs[kk][tx * 4]; \
        ACC[0][0] += a4.x*b4.x; ACC[0][1] += a4.x*b4.y; ACC[0][2] += a4.x*b4.z; ACC[0][3] += a4.x*b4.w; \
        ACC[1][0] += a4.y*b4.x; ACC[1][1] += a4.y*b4.y; ACC[1][2] += a4.y*b4.z; ACC[1][3] += a4.y*b4.w; \
        ACC[2][0] += a4.z*b4.x; ACC[2][1] += a4.z*b4.y; ACC[2][2] += a4.z*b4.z; ACC[2][3] += a4.z*b4.w; \
        ACC[3][0] += a4.w*b4.x; ACC[3][1] += a4.w*b4.y; ACC[3][2] += a4.w*b4.z; ACC[3][3] += a4.w*b4.w; \
    }

// PASS 1: per-(row, col-tile) partial stats (+ optional logit store)
// PASS 2: recompute fallback — accumulate avg_probs column sums
template<int PASS, bool STOREL>
__global__ __launch_bounds__(256) void k_gemm(
    const float* __restrict__ zn, const float* __restrict__ en,
    const float* __restrict__ z2t, const float* __restrict__ z2g,
    const float* __restrict__ e2t, const float* __restrict__ e2g,
    float* __restrict__ pm, float* __restrict__ pZ, float* __restrict__ pS1,
    float* __restrict__ pdmin, float* __restrict__ pdt2, float* __restrict__ pdg2,
    int* __restrict__ pidx, float* __restrict__ lmat,
    const float* __restrict__ lse, float* __restrict__ avgp)
{
    const int nj = blockIdx.x, bi = blockIdx.y;
    const int t = threadIdx.x, tx = t & 15, ty = t >> 4;
    __shared__ __align__(16) float As[16][68];
    __shared__ __align__(16) float Bs[16][68];
    float at[4][4] = {{0.f}}, ag[4][4] = {{0.f}};

    const int lrow = t >> 2, lcg = t & 3;
    const float* aptr = zn + (size_t)(bi * 64 + lrow) * KD + (size_t)lcg * 4;
    const float* bptr = en + (size_t)(nj * 64 + lrow) * KD + (size_t)lcg * 4;
    float4 av = *(const float4*)aptr;
    float4 bv = *(const float4*)bptr;

    for (int kt = 0; kt < 64; ++kt) {
        __syncthreads();
        As[lcg * 4 + 0][lrow] = av.x; As[lcg * 4 + 1][lrow] = av.y;
        As[lcg * 4 + 2][lrow] = av.z; As[lcg * 4 + 3][lrow] = av.w;
        Bs[lcg * 4 + 0][lrow] = bv.x; Bs[lcg * 4 + 1][lrow] = bv.y;
        Bs[lcg * 4 + 2][lrow] = bv.z; Bs[lcg * 4 + 3][lrow] = bv.w;
        __syncthreads();
        if (kt < 63) {
            av = *(const float4*)(aptr + (size_t)(kt + 1) * 16);
            bv = *(const float4*)(bptr + (size_t)(kt + 1) * 16);
        }
        if (kt < 32) { GEMM_STEP(at) } else { GEMM_STEP(ag) }
    }

    const int row0 = bi * 64 + ty * 4;
    const int col0 = nj * 64 + tx * 4;
    float z2tr[4], z2gr[4], e2tc[4], e2gc[4];
#pragma unroll
    for (int i = 0; i < 4; ++i) { z2tr[i] = z2t[row0 + i]; z2gr[i] = z2g[row0 + i]; }
#pragma unroll
    for (int j = 0; j < 4; ++j) { e2tc[j] = e2t[col0 + j]; e2gc[j] = e2g[col0 + j]; }

    if constexpr (PASS == 1) {
#pragma unroll 1
        for (int i = 0; i < 4; ++i) {
            float lrowv[4];
            float dt2 = 0.f, dg2 = 0.f;
            float dmin = 3.0e38f; int didx = 0x7fffffff;
#pragma unroll
            for (int j = 0; j < 4; ++j) {
                float dtv = (z2tr[i] + e2tc[j]) - 2.0f * at[i][j];
                float dgv = (z2gr[i] + e2gc[j]) - 2.0f * ag[i][j];
                float dd = dtv + dgv;
                dt2 += dtv * dtv; dg2 += dgv * dgv;
                lrowv[j] = (-dd) / 0.01f;
                int c = col0 + j;
                if (dd < dmin) { dmin = dd; didx = c; }
            }
            if constexpr (STOREL) {
                float4 l4; l4.x = lrowv[0]; l4.y = lrowv[1]; l4.z = lrowv[2]; l4.w = lrowv[3];
                *(float4*)(lmat + (size_t)(row0 + i) * NEc + col0) = l4;
            }
            // 16-lane (same-ty group, contiguous in wave) reductions
            float m = fmaxf(fmaxf(lrowv[0], lrowv[1]), fmaxf(lrowv[2], lrowv[3]));
#pragma unroll
            for (int s = 1; s < 16; s <<= 1) m = fmaxf(m, __shfl_xor(m, s));
            float Z = 0.f, S1 = 0.f;
#pragma unroll
            for (int j = 0; j < 4; ++j) {
                float e = expf(lrowv[j] - m);
                Z += e; S1 += e * lrowv[j];
            }
#pragma unroll
            for (int s = 1; s < 16; s <<= 1) {
                Z   += __shfl_xor(Z, s);
                S1  += __shfl_xor(S1, s);
                dt2 += __shfl_xor(dt2, s);
                dg2 += __shfl_xor(dg2, s);
            }
#pragma unroll
            for (int s = 1; s < 16; s <<= 1) {
                float ov = __shfl_xor(dmin, s);
                int   oi = __shfl_xor(didx, s);
                if (ov < dmin || (ov == dmin && oi < didx)) { dmin = ov; didx = oi; }
            }
            if (tx == 0) {
                size_t pb = (size_t)(row0 + i) * NJ + nj;
                pm[pb] = m; pZ[pb] = Z; pS1[pb] = S1;
                pdmin[pb] = dmin; pdt2[pb] = dt2; pdg2[pb] = dg2; pidx[pb] = didx;
            }
        }
    } else {
        __shared__ float colsum[64];
        if (t < 64) colsum[t] = 0.f;
        __syncthreads();
        float lser[4];
#pragma unroll
        for (int i = 0; i < 4; ++i) lser[i] = lse[row0 + i];
#pragma unroll
        for (int j = 0; j < 4; ++j) {
            float s = 0.f;
#pragma unroll
            for (int i = 0; i < 4; ++i) {
                float dtv = (z2tr[i] + e2tc[j]) - 2.0f * at[i][j];
                float dgv = (z2gr[i] + e2gc[j]) - 2.0f * ag[i][j];
                float dd = dtv + dgv;
                float lv = (-dd) / 0.01f;
                s += expf(lv - lser[i]);
            }
            atomicAdd(&colsum[tx * 4 + j], s);
        }
        __syncthreads();
        if (t < 64) atomicAdd(&avgp[nj * 64 + t], colsum[t]);
    }
}

// store-path pass 2: column sums of p = exp(l - lse[b]) from stored logits
__global__ __launch_bounds__(256) void k_colsum(const float* __restrict__ lmat,
                                                const float* __restrict__ lse,
                                                float* __restrict__ avgp) {
    int col = blockIdx.x * 256 + threadIdx.x;
    int b0 = blockIdx.y * 512;
    float acc = 0.f;
    for (int b = b0; b < b0 + 512; ++b) {
        acc += expf(lmat[(size_t)b * NEc + col] - lse[b]);
    }
    atomicAdd(&avgp[col], acc);
}

// merge the NJ=128 per-tile partials of each row
__global__ __launch_bounds__(128) void k_rowreduce(
    const float* __restrict__ pm, const float* __restrict__ pZ, const float* __restrict__ pS1,
    const float* __restrict__ pdmin, const float* __restrict__ pdt2, const float* __restrict__ pdg2,
    const int* __restrict__ pidx,
    float* __restrict__ lse, int* __restrict__ idxo, float* __restrict__ scal,
    float* __restrict__ out)
{
    int b = blockIdx.x, t = threadIdx.x;
    size_t pb = (size_t)b * NJ + t;
    __shared__ float red[128];
    __shared__ int redi[128];

    float m = pm[pb];
    red[t] = m; __syncthreads();
    for (int s = 64; s > 0; s >>= 1) { if (t < s) red[t] = fmaxf(red[t], red[t + s]); __syncthreads(); }
    float M = red[0]; __syncthreads();

    float sc = expf(m - M);
    red[t] = pZ[pb] * sc; __syncthreads();
    for (int s = 64; s > 0; s >>= 1) { if (t < s) red[t] += red[t + s]; __syncthreads(); }
    float Z = red[0]; __syncthreads();

    red[t] = pS1[pb] * sc; __syncthreads();
    for (int s = 64; s > 0; s >>= 1) { if (t < s) red[t] += red[t + s]; __syncthreads(); }
    float S1 = red[0]; __syncthreads();

    red[t] = pdt2[pb]; __syncthreads();
    for (int s = 64; s > 0; s >>= 1) { if (t < s) red[t] += red[t + s]; __syncthreads(); }
    float dt2 = red[0]; __syncthreads();

    red[t] = pdg2[pb]; __syncthreads();
    for (int s = 64; s > 0; s >>= 1) { if (t < s) red[t] += red[t + s]; __syncthreads(); }
    float dg2 = red[0]; __syncthreads();

    red[t] = pdmin[pb]; redi[t] = pidx[pb]; __syncthreads();
    for (int s = 64; s > 0; s >>= 1) {
        if (t < s) {
            if (red[t + s] < red[t] || (red[t + s] == red[t] && redi[t + s] < redi[t])) {
                red[t] = red[t + s]; redi[t] = redi[t + s];
            }
        }
        __syncthreads();
    }

    if (t == 0) {
        float lseb = M + logf(Z);
        lse[b] = lseb;
        idxo[b] = redi[0];
        out[O_IX + b] = (float)redi[0];
        atomicAdd(&scal[1], lseb - S1 / Z);  // sample-entropy sum
        atomicAdd(&scal[2], dt2);            // text_d_norm sum
        atomicAdd(&scal[3], dg2);            // graph_d_norm sum
    }
}

// gather z_q outputs + vq reduction
__global__ __launch_bounds__(256) void k_gather(const float* __restrict__ en, const float* __restrict__ zn,
                                                const int* __restrict__ idxi, float* __restrict__ out,
                                                float* __restrict__ scal) {
    int b = blockIdx.x, t = threadIdx.x;
    int idx = idxi[b];
    const float4 e = *(const float4*)(en + (size_t)idx * KD + (size_t)t * 4);
    const float4 zv = *(const float4*)(zn + (size_t)b * KD + (size_t)t * 4);
    float dx = e.x - zv.x, dy = e.y - zv.y, dz = e.z - zv.z, dw = e.w - zv.w;
    float4 o;
    o.x = zv.x + dx; o.y = zv.y + dy; o.z = zv.z + dz; o.w = zv.w + dw;  // z_norm + (z_q - z_norm)
    *(float4*)(out + (size_t)b * KD + (size_t)t * 4) = o;
    float ss = dx*dx + dy*dy + dz*dz + dw*dw;

    // z_q_text / z_q_graph (odd float offsets -> scalar, coalesced)
    for (int c = t; c < KD; c += 256) {
        float ev = en[(size_t)idx * KD + c];
        if (c < DH) out[O_ZT + (size_t)b * DH + c] = ev;
        else        out[O_ZG + (size_t)b * DH + (c - DH)] = ev;
    }

    __shared__ float red[256];
    red[t] = ss; __syncthreads();
    for (int s = 128; s > 0; s >>= 1) { if (t < s) red[t] += red[t + s]; __syncthreads(); }
    if (t == 0) atomicAdd(&scal[0], red[0]);
}

__global__ __launch_bounds__(256) void k_finalize(const float* __restrict__ avgp,
                                                  const float* __restrict__ scal,
                                                  float* __restrict__ out) {
    int t = threadIdx.x;
    float s = 0.f;
    for (int n = t; n < NEc; n += 256) {
        float a = avgp[n] * (1.0f / 8192.0f);
        s -= a * logf(a + 1e-5f);
    }
    __shared__ float red[256];
    red[t] = s; __syncthreads();
    for (int st = 128; st > 0; st >>= 1) { if (t < st) red[t] += red[t + st]; __syncthreads(); }
    if (t == 0) {
        float aent = red[0];
        float vq = scal[0] * (1.0f / 8388608.0f);
        float se = scal[1] * (1.0f / 8192.0f);
        out[O_VQ]  = vq;
        out[O_CM]  = 0.25f * vq;
        out[O_ENT] = 0.1f * (se - aent);
        out[O_TD]  = scal[2] * (1.0f / 8192.0f);
        out[O_GD]  = scal[3] * (1.0f / 8192.0f);
    }
}

extern "C" void kernel_launch(void* const* d_in, const int* in_sizes, int n_in,
                              void* d_out, int out_size, void* d_ws, size_t ws_size,
                              hipStream_t stream) {
    const float* z  = (const float*)d_in[0];
    const float* et = (const float*)d_in[1];
    const float* eg = (const float*)d_in[2];
    float* out = (float*)d_out;
    float* ws  = (float*)d_ws;

    float* zn   = ws + WS_ZN;
    float* en   = ws + WS_EN;
    float* z2t  = ws + WS_Z2T;
    float* z2g  = ws + WS_Z2G;
    float* e2t  = ws + WS_E2T;
    float* e2g  = ws + WS_E2G;
    float* pm   = ws + WS_PM;
    float* pZ   = ws + WS_PZ;
    float* pS1  = ws + WS_PS1;
    float* pdmin= ws + WS_PDMIN;
    float* pdt2 = ws + WS_PDT2;
    float* pdg2 = ws + WS_PDG2;
    int*   pidx = (int*)(ws + WS_PIDX);
    float* lsep = ws + WS_LSE;
    int*   idxi = (int*)(ws + WS_IDX);
    float* avgp = ws + WS_AVGP;
    float* scal = ws + WS_SCAL;
    float* lmat = ws + WS_LMAT;

    bool storel = (ws_size >= WS_STORE_END * sizeof(float));

    k_zero<<<(8208 + 255) / 256, 256, 0, stream>>>(avgp, 8208);  // avgp (8192) + scal (16) contiguous
    k_norm_z<<<BB, 256, 0, stream>>>(z, zn, z2t, z2g);
    k_norm_e<<<NEc, 256, 0, stream>>>(et, eg, en, e2t, e2g);

    dim3 gg(NJ, BB / 64);
    if (storel) {
        k_gemm<1, true><<<gg, 256, 0, stream>>>(zn, en, z2t, z2g, e2t, e2g,
                                                pm, pZ, pS1, pdmin, pdt2, pdg2, pidx,
                                                lmat, lsep, avgp);
    } else {
        k_gemm<1, false><<<gg, 256, 0, stream>>>(zn, en, z2t, z2g, e2t, e2g,
                                                 pm, pZ, pS1, pdmin, pdt2, pdg2, pidx,
                                                 lmat, lsep, avgp);
    }
    k_rowreduce<<<BB, 128, 0, stream>>>(pm, pZ, pS1, pdmin, pdt2, pdg2, pidx,
                                        lsep, idxi, scal, out);
    if (storel) {
        k_colsum<<<dim3(32, 16), 256, 0, stream>>>(lmat, lsep, avgp);
    } else {
        k_gemm<2, false><<<gg, 256, 0, stream>>>(zn, en, z2t, z2g, e2t, e2g,
                                                 pm, pZ, pS1, pdmin, pdt2, pdg2, pidx,
                                                 lmat, lsep, avgp);
    }
    k_gather<<<BB, 256, 0, stream>>>(en, zn, idxi, out, scal);
    k_finalize<<<1, 256, 0, stream>>>(avgp, scal, out);
}

// Round 2
// 1171.752 us; speedup vs baseline: 3.6981x; 3.6981x over previous
//
#include <hip/hip_runtime.h>
#include <cmath>

using f32x4 = __attribute__((ext_vector_type(4))) float;
using f16x8 = __attribute__((ext_vector_type(8))) _Float16;

#define BB   8192
#define NEc  8192
#define NJ2  64      // 8192 / 128 column blocks

// ---------------- workspace layout (float units) ----------------
#define WS_ZH   ((size_t)0)                 // 8192x1024 halves = 4.19M floats
#define WS_ZL   (WS_ZH + 4194304)
#define WS_EH   (WS_ZL + 4194304)
#define WS_EL   (WS_EH + 4194304)
#define WS_Z2T  (WS_EL + 4194304)
#define WS_Z2G  (WS_Z2T + 8192)
#define WS_E2T  (WS_Z2G + 8192)
#define WS_E2G  (WS_E2T + 8192)
#define NPART   ((size_t)8192*64)
#define WS_PM   (WS_E2G + 8192)
#define WS_PZ   (WS_PM + NPART)
#define WS_PS1  (WS_PZ + NPART)
#define WS_PDM  (WS_PS1 + NPART)
#define WS_PDT  (WS_PDM + NPART)
#define WS_PDG  (WS_PDT + NPART)
#define WS_PIX  (WS_PDG + NPART)            // int
#define WS_LSE  (WS_PIX + NPART)
#define WS_IDX  (WS_LSE + 8192)             // int
#define WS_AVGP (WS_IDX + 8192)
#define WS_SCAL (WS_AVGP + 8192)
#define WS_BASE_END (WS_SCAL + 16)
#define WS_QM   WS_BASE_END                 // 8192x8192 bf16 = 33.55M floats
#define WS_STORE_END (WS_QM + 33554432)

// ---------------- output layout (floats) ----------------
#define O_ZQ  ((size_t)0)
#define O_VQ  ((size_t)8388608)
#define O_CM  ((size_t)8388609)
#define O_ENT ((size_t)8388610)
#define O_TD  ((size_t)8388611)
#define O_GD  ((size_t)8388612)
#define O_ZT  ((size_t)8388613)
#define O_ZG  (O_ZT + (size_t)8192*512)
#define O_IX  (O_ZG + (size_t)8192*512)

// hi scale 256 (keeps fp16 hi out of subnormals), lo scale 4096 relative to hi
#define SCL_H    256.0f
#define INV_HH   (1.0f/65536.0f)            // 1/SCL_H^2

__device__ __forceinline__ size_t tiled_off(int row, int chunk) {
    // chunk = k/8 in [0,128). layout: [rowblk][kt][slot][row&127][8]
    return (((size_t)(row >> 7) * 32 + (chunk >> 2)) * 4 + (size_t)(chunk & 3)) * 1024
           + (size_t)(row & 127) * 8;
}

__device__ __forceinline__ void gload16(const void* g, void* l) {
    __builtin_amdgcn_global_load_lds(
        (const __attribute__((address_space(1))) unsigned int*)g,
        (__attribute__((address_space(3))) unsigned int*)l, 16, 0, 0);
}

__device__ __forceinline__ f32x4 mfma16(f16x8 a, f16x8 b, f32x4 c) {
    return __builtin_amdgcn_mfma_f32_16x16x32_f16(a, b, c, 0, 0, 0);
}

__device__ __forceinline__ unsigned short f2bf(float x) {
    unsigned int u = __float_as_uint(x);
    return (unsigned short)((u + 0x7fffu + ((u >> 16) & 1u)) >> 16);
}
__device__ __forceinline__ float bf2f(unsigned short u) {
    return __uint_as_float(((unsigned int)u) << 16);
}

__global__ __launch_bounds__(256) void k_zero(float* __restrict__ p, int n) {
    int i = blockIdx.x * 256 + threadIdx.x;
    if (i < n) p[i] = 0.0f;
}

// ---- normalize z rows (halves independently), write fp16 hi/lo tiled + sq-sums ----
__global__ __launch_bounds__(256) void k_norm_z(const float* __restrict__ z,
                                                _Float16* __restrict__ zh, _Float16* __restrict__ zl,
                                                float* __restrict__ z2t, float* __restrict__ z2g) {
    int t = threadIdx.x;
    int rin = t >> 7, c = t & 127;
    int row = blockIdx.x * 2 + rin;
    const float* src = z + (size_t)row * 1024 + (size_t)c * 8;
    float4 v0 = *(const float4*)src;
    float4 v1 = *(const float4*)(src + 4);
    float v[8] = {v0.x, v0.y, v0.z, v0.w, v1.x, v1.y, v1.z, v1.w};
    float ss = 0.f;
#pragma unroll
    for (int e = 0; e < 8; ++e) ss += v[e] * v[e];
    __shared__ float red[256];
    red[t] = ss; __syncthreads();
    for (int s = 32; s > 0; s >>= 1) { if ((t & 63) < s) red[t] += red[t + s]; __syncthreads(); }
    float nrm = sqrtf(red[t & 192]);
    float nv[8];
#pragma unroll
    for (int e = 0; e < 8; ++e) nv[e] = v[e] / nrm;
    float s2 = 0.f;
#pragma unroll
    for (int e = 0; e < 8; ++e) s2 += nv[e] * nv[e];
    __syncthreads();
    red[t] = s2; __syncthreads();
    for (int s = 32; s > 0; s >>= 1) { if ((t & 63) < s) red[t] += red[t + s]; __syncthreads(); }
    if ((t & 63) == 0) {
        if (t & 64) z2g[row] = red[t]; else z2t[row] = red[t];
    }
    f16x8 h8, l8;
#pragma unroll
    for (int e = 0; e < 8; ++e) {
        float xs = nv[e] * SCL_H;
        _Float16 h = (_Float16)xs;
        h8[e] = h;
        l8[e] = (_Float16)((xs - (float)h) * 4096.0f);
    }
    size_t off = tiled_off(row, c);
    *(f16x8*)(zh + off) = h8;
    *(f16x8*)(zl + off) = l8;
}

// ---- normalize emb rows (text k<512, graph k>=512), same tiled fp16 output ----
__global__ __launch_bounds__(256) void k_norm_e(const float* __restrict__ et, const float* __restrict__ eg,
                                                _Float16* __restrict__ eh, _Float16* __restrict__ el,
                                                float* __restrict__ e2t, float* __restrict__ e2g) {
    int t = threadIdx.x;
    int rin = t >> 7, c = t & 127;
    int row = blockIdx.x * 2 + rin;
    const float* src = (c < 64) ? (et + (size_t)row * 512 + (size_t)c * 8)
                                : (eg + (size_t)row * 512 + (size_t)(c - 64) * 8);
    float4 v0 = *(const float4*)src;
    float4 v1 = *(const float4*)(src + 4);
    float v[8] = {v0.x, v0.y, v0.z, v0.w, v1.x, v1.y, v1.z, v1.w};
    float ss = 0.f;
#pragma unroll
    for (int e = 0; e < 8; ++e) ss += v[e] * v[e];
    __shared__ float red[256];
    red[t] = ss; __syncthreads();
    for (int s = 32; s > 0; s >>= 1) { if ((t & 63) < s) red[t] += red[t + s]; __syncthreads(); }
    float nrm = sqrtf(red[t & 192]);
    float nv[8];
#pragma unroll
    for (int e = 0; e < 8; ++e) nv[e] = v[e] / nrm;
    float s2 = 0.f;
#pragma unroll
    for (int e = 0; e < 8; ++e) s2 += nv[e] * nv[e];
    __syncthreads();
    red[t] = s2; __syncthreads();
    for (int s = 32; s > 0; s >>= 1) { if ((t & 63) < s) red[t] += red[t + s]; __syncthreads(); }
    if ((t & 63) == 0) {
        if (t & 64) e2g[row] = red[t]; else e2t[row] = red[t];
    }
    f16x8 h8, l8;
#pragma unroll
    for (int e = 0; e < 8; ++e) {
        float xs = nv[e] * SCL_H;
        _Float16 h = (_Float16)xs;
        h8[e] = h;
        l8[e] = (_Float16)((xs - (float)h) * 4096.0f);
    }
    size_t off = tiled_off(row, c);
    *(f16x8*)(eh + off) = h8;
    *(f16x8*)(el + off) = l8;
}

// ---- MFMA distance GEMM: 128x128 tile, 8 waves (2x4), wave 64x32, fp16 split-2 ----
template<int PASS, bool STOREQ>
__global__ __launch_bounds__(512, 2) void k_gemm(
    const _Float16* __restrict__ zht, const _Float16* __restrict__ zlt,
    const _Float16* __restrict__ eht, const _Float16* __restrict__ elt,
    const float* __restrict__ z2t, const float* __restrict__ z2g,
    const float* __restrict__ e2t, const float* __restrict__ e2g,
    float* __restrict__ pm, float* __restrict__ pz, float* __restrict__ ps1,
    float* __restrict__ pdm, float* __restrict__ pdt, float* __restrict__ pdg,
    int* __restrict__ pix, unsigned short* __restrict__ qm,
    const float* __restrict__ lse, float* __restrict__ avgp)
{
    const int nj = blockIdx.x, bi = blockIdx.y;
    const int t = threadIdx.x;
    const int lane = t & 63, wid = t >> 6;
    const int wave_r = wid >> 2, wave_c = wid & 3;
    const int jf = lane & 15, g = lane >> 4;

    __shared__ __align__(16) _Float16 lAh[2][4096];
    __shared__ __align__(16) _Float16 lAl[2][4096];
    __shared__ __align__(16) _Float16 lBh[2][4096];
    __shared__ __align__(16) _Float16 lBl[2][4096];
    __shared__ float sM[128][4], sDt[128][4], sDg[128][4], sDm[128][4], sZ[128][4], sS1[128][4];
    __shared__ int   sIx[128][4];
    __shared__ float sMf[128];
    __shared__ float scol[128];

    if (PASS == 2 && t < 128) scol[t] = 0.f;

    f32x4 acct[4][2] = {};
    f32x4 accg[4][2] = {};
    f32x4 accx[4][2] = {};

#define STAGE(KT, B) { \
        size_t ta = ((size_t)(bi * 32 + (KT))) * 4096 + (size_t)t * 8; \
        size_t tb = ((size_t)(nj * 32 + (KT))) * 4096 + (size_t)t * 8; \
        gload16(zht + ta, &lAh[B][t * 8]); \
        gload16(zlt + ta, &lAl[B][t * 8]); \
        gload16(eht + tb, &lBh[B][t * 8]); \
        gload16(elt + tb, &lBl[B][t * 8]); }

    int cur = 0;
    STAGE(0, 0)
    asm volatile("s_waitcnt vmcnt(0)" ::: "memory");
    __syncthreads();

    for (int kt = 0; kt < 32; ++kt) {
        if (kt + 1 < 32) {
            if (cur == 0) STAGE(kt + 1, 1) else STAGE(kt + 1, 0)
        }
        f16x8 ah[4], al[4], bh[2], bl[2];
#pragma unroll
        for (int fr = 0; fr < 4; ++fr) {
            int off = g * 1024 + (wave_r * 64 + fr * 16 + jf) * 8;
            ah[fr] = *(const f16x8*)&lAh[cur][off];
            al[fr] = *(const f16x8*)&lAl[cur][off];
        }
#pragma unroll
        for (int fc = 0; fc < 2; ++fc) {
            int off = g * 1024 + (wave_c * 32 + fc * 16 + jf) * 8;
            bh[fc] = *(const f16x8*)&lBh[cur][off];
            bl[fc] = *(const f16x8*)&lBl[cur][off];
        }
        if (kt < 16) {
#pragma unroll
            for (int fr = 0; fr < 4; ++fr)
#pragma unroll
            for (int fc = 0; fc < 2; ++fc) {
                acct[fr][fc] = mfma16(ah[fr], bh[fc], acct[fr][fc]);
                accx[fr][fc] = mfma16(ah[fr], bl[fc], accx[fr][fc]);
                accx[fr][fc] = mfma16(al[fr], bh[fc], accx[fr][fc]);
            }
        } else {
#pragma unroll
            for (int fr = 0; fr < 4; ++fr)
#pragma unroll
            for (int fc = 0; fc < 2; ++fc) {
                accg[fr][fc] = mfma16(ah[fr], bh[fc], accg[fr][fc]);
                accx[fr][fc] = mfma16(ah[fr], bl[fc], accx[fr][fc]);
                accx[fr][fc] = mfma16(al[fr], bh[fc], accx[fr][fc]);
            }
        }
        asm volatile("s_waitcnt vmcnt(0)" ::: "memory");
        __syncthreads();
        cur ^= 1;
    }
#undef STAGE

    const int colbase = nj * 128 + wave_c * 32;
    float e2tc[2], e2gc[2];
#pragma unroll
    for (int fc = 0; fc < 2; ++fc) {
        e2tc[fc] = e2t[colbase + fc * 16 + jf];
        e2gc[fc] = e2g[colbase + fc * 16 + jf];
    }

    if constexpr (PASS == 1) {
        // stage 1: per-row (over this wave's 32 cols) max / dmin / dt2 / dg2; keep l in acct
#pragma unroll
        for (int fr = 0; fr < 4; ++fr) {
#pragma unroll
            for (int reg = 0; reg < 4; ++reg) {
                int rl = wave_r * 64 + fr * 16 + g * 4 + reg;
                int i  = bi * 128 + rl;
                float z2ti = z2t[i], z2gi = z2g[i];
                float mrow = -3.0e38f, dmin = 3.0e38f, dt2 = 0.f, dg2 = 0.f;
                int dix = 0;
#pragma unroll
                for (int fc = 0; fc < 2; ++fc) {
                    float ht = acct[fr][fc][reg], hg = accg[fr][fc][reg], xx = accx[fr][fc][reg];
                    float dta = z2ti + e2tc[fc] - ht * (2.0f * INV_HH);
                    float dga = z2gi + e2gc[fc] - hg * (2.0f * INV_HH);
                    float d   = (z2ti + z2gi) + (e2tc[fc] + e2gc[fc])
                              - 2.0f * INV_HH * (ht + hg + xx * (1.0f / 4096.0f));
                    float lv  = -100.0f * d;
                    acct[fr][fc][reg] = lv;   // reuse as logit storage
                    dt2 += dta * dta; dg2 += dga * dga;
                    int j = colbase + fc * 16 + jf;
                    if (d < dmin) { dmin = d; dix = j; }
                    mrow = fmaxf(mrow, lv);
                }
#pragma unroll
                for (int s = 1; s < 16; s <<= 1) {
                    mrow = fmaxf(mrow, __shfl_xor(mrow, s));
                    dt2 += __shfl_xor(dt2, s);
                    dg2 += __shfl_xor(dg2, s);
                    float ov = __shfl_xor(dmin, s); int oi = __shfl_xor(dix, s);
                    if (ov < dmin || (ov == dmin && oi < dix)) { dmin = ov; dix = oi; }
                }
                if (jf == 0) {
                    sM[rl][wave_c] = mrow; sDt[rl][wave_c] = dt2; sDg[rl][wave_c] = dg2;
                    sDm[rl][wave_c] = dmin; sIx[rl][wave_c] = dix;
                }
            }
        }
        __syncthreads();
        if (t < 128) {
            sMf[t] = fmaxf(fmaxf(sM[t][0], sM[t][1]), fmaxf(sM[t][2], sM[t][3]));
        }
        __syncthreads();
        // stage 2: Z, S1 vs merged block max; optional q store
#pragma unroll
        for (int fr = 0; fr < 4; ++fr) {
#pragma unroll
            for (int reg = 0; reg < 4; ++reg) {
                int rl = wave_r * 64 + fr * 16 + g * 4 + reg;
                float M = sMf[rl];
                float Z = 0.f, S1 = 0.f;
#pragma unroll
                for (int fc = 0; fc < 2; ++fc) {
                    float lv = acct[fr][fc][reg];
                    float e  = expf(lv - M);
                    Z += e; S1 += e * lv;
                    if constexpr (STOREQ) {
                        size_t qo = (size_t)(bi * 128 + rl) * 8192 + (colbase + fc * 16 + jf);
                        qm[qo] = f2bf(e);
                    }
                }
#pragma unroll
                for (int s = 1; s < 16; s <<= 1) {
                    Z  += __shfl_xor(Z, s);
                    S1 += __shfl_xor(S1, s);
                }
                if (jf == 0) { sZ[rl][wave_c] = Z; sS1[rl][wave_c] = S1; }
            }
        }
        __syncthreads();
        if (t < 128) {
            float M = sMf[t];
            float Z = sZ[t][0] + sZ[t][1] + sZ[t][2] + sZ[t][3];
            float S1 = sS1[t][0] + sS1[t][1] + sS1[t][2] + sS1[t][3];
            float dt2 = sDt[t][0] + sDt[t][1] + sDt[t][2] + sDt[t][3];
            float dg2 = sDg[t][0] + sDg[t][1] + sDg[t][2] + sDg[t][3];
            float dmin = sDm[t][0]; int dix = sIx[t][0];
#pragma unroll
            for (int w = 1; w < 4; ++w) {
                float ov = sDm[t][w]; int oi = sIx[t][w];
                if (ov < dmin || (ov == dmin && oi < dix)) { dmin = ov; dix = oi; }
            }
            size_t pb = (size_t)(bi * 128 + t) * 64 + nj;
            pm[pb] = M; pz[pb] = Z; ps1[pb] = S1;
            pdm[pb] = dmin; pdt[pb] = dt2; pdg[pb] = dg2; pix[pb] = dix;
        }
    } else {
        // PASS 2: recompute p = exp(l - lse), column sums
        float cs0 = 0.f, cs1 = 0.f;
#pragma unroll
        for (int fr = 0; fr < 4; ++fr) {
#pragma unroll
            for (int reg = 0; reg < 4; ++reg) {
                int rl = wave_r * 64 + fr * 16 + g * 4 + reg;
                int i  = bi * 128 + rl;
                float z2ti = z2t[i], z2gi = z2g[i];
                float lsei = lse[i];
#pragma unroll
                for (int fc = 0; fc < 2; ++fc) {
                    float ht = acct[fr][fc][reg], hg = accg[fr][fc][reg], xx = accx[fr][fc][reg];
                    float d = (z2ti + z2gi) + (e2tc[fc] + e2gc[fc])
                            - 2.0f * INV_HH * (ht + hg + xx * (1.0f / 4096.0f));
                    float lv = -100.0f * d;
                    float p = expf(lv - lsei);
                    if (fc == 0) cs0 += p; else cs1 += p;
                }
            }
        }
        cs0 += __shfl_xor(cs0, 16); cs0 += __shfl_xor(cs0, 32);
        cs1 += __shfl_xor(cs1, 16); cs1 += __shfl_xor(cs1, 32);
        if (g == 0) {
            atomicAdd(&scol[wave_c * 32 + jf], cs0);
            atomicAdd(&scol[wave_c * 32 + 16 + jf], cs1);
        }
        __syncthreads();
        if (t < 128) atomicAdd(&avgp[nj * 128 + t], scol[t]);
    }
}

// ---- merge the 64 per-column-block partials of each row (one wave per row) ----
__global__ __launch_bounds__(64) void k_rowreduce(
    const float* __restrict__ pm, const float* __restrict__ pz, const float* __restrict__ ps1,
    const float* __restrict__ pdm, const float* __restrict__ pdt, const float* __restrict__ pdg,
    const int* __restrict__ pix,
    float* __restrict__ lse, int* __restrict__ idxo, float* __restrict__ scal,
    float* __restrict__ out)
{
    int b = blockIdx.x, t = threadIdx.x;
    size_t pb = (size_t)b * 64 + t;
    float m = pm[pb];
#pragma unroll
    for (int s = 1; s < 64; s <<= 1) m = fmaxf(m, __shfl_xor(m, s));
    float sc = expf(pm[pb] - m);
    float Z = pz[pb] * sc, S1 = ps1[pb] * sc;
    float dt2 = pdt[pb], dg2 = pdg[pb];
    float dmin = pdm[pb]; int dix = pix[pb];
#pragma unroll
    for (int s = 1; s < 64; s <<= 1) {
        Z += __shfl_xor(Z, s); S1 += __shfl_xor(S1, s);
        dt2 += __shfl_xor(dt2, s); dg2 += __shfl_xor(dg2, s);
        float ov = __shfl_xor(dmin, s); int oi = __shfl_xor(dix, s);
        if (ov < dmin || (ov == dmin && oi < dix)) { dmin = ov; dix = oi; }
    }
    if (t == 0) {
        float l = m + logf(Z);
        lse[b] = l; idxo[b] = dix;
        out[O_IX + b] = (float)dix;
        atomicAdd(&scal[1], l - S1 / Z);
        atomicAdd(&scal[2], dt2);
        atomicAdd(&scal[3], dg2);
    }
}

// ---- stored-q column sums: avgp[n] += sum_b q[b][n] * exp(pm - lse) ----
__global__ __launch_bounds__(256) void k_colsumq(const unsigned short* __restrict__ qm,
                                                 const float* __restrict__ pm,
                                                 const float* __restrict__ lse,
                                                 float* __restrict__ avgp) {
    int cc = blockIdx.x;       // 64 col blocks of 128
    int rb = blockIdx.y;       // 32 row blocks of 256
    int t = threadIdx.x;
    int jf = t & 15, rg = t >> 4;
    float acc[8] = {0.f};
    for (int it = 0; it < 16; ++it) {
        int r = rb * 256 + it * 16 + rg;
        float scale = expf(pm[(size_t)r * 64 + cc] - lse[r]);
        const unsigned short* qrow = qm + (size_t)r * 8192 + cc * 128 + jf * 8;
        uint4 q4 = *(const uint4*)qrow;
        unsigned int w[4] = {q4.x, q4.y, q4.z, q4.w};
#pragma unroll
        for (int p = 0; p < 4; ++p) {
            acc[2 * p]     += bf2f((unsigned short)(w[p] & 0xffffu)) * scale;
            acc[2 * p + 1] += bf2f((unsigned short)(w[p] >> 16)) * scale;
        }
    }
    __shared__ float scol[128];
    if (t < 128) scol[t] = 0.f;
    __syncthreads();
#pragma unroll
    for (int e = 0; e < 8; ++e) atomicAdd(&scol[jf * 8 + e], acc[e]);
    __syncthreads();
    if (t < 128) atomicAdd(&avgp[cc * 128 + t], scol[t]);
}

// ---- gather z_q outputs + vq reduction (reconstruct fp32 from hi/lo) ----
__global__ __launch_bounds__(128) void k_gather(
    const _Float16* __restrict__ zh, const _Float16* __restrict__ zl,
    const _Float16* __restrict__ eh, const _Float16* __restrict__ el,
    const int* __restrict__ idxi, float* __restrict__ out, float* __restrict__ scal)
{
    int b = blockIdx.x, t = threadIdx.x;  // t in [0,128) = k-chunk
    int idx = idxi[b];
    size_t zo = tiled_off(b, t), eo = tiled_off(idx, t);
    f16x8 zh8 = *(const f16x8*)(zh + zo);
    f16x8 zl8 = *(const f16x8*)(zl + zo);
    f16x8 eh8 = *(const f16x8*)(eh + eo);
    f16x8 el8 = *(const f16x8*)(el + eo);
    float zq[8], oz[8];
    float ss = 0.f;
#pragma unroll
    for (int e = 0; e < 8; ++e) {
        float zn = ((float)zh8[e] + (float)zl8[e] * (1.0f / 4096.0f)) * (1.0f / SCL_H);
        float eq = ((float)eh8[e] + (float)el8[e] * (1.0f / 4096.0f)) * (1.0f / SCL_H);
        float df = eq - zn;
        zq[e] = eq;
        oz[e] = zn + df;
        ss += df * df;
    }
    float* dst = out + O_ZQ + (size_t)b * 1024 + (size_t)t * 8;
    *(float4*)dst       = make_float4(oz[0], oz[1], oz[2], oz[3]);
    *(float4*)(dst + 4) = make_float4(oz[4], oz[5], oz[6], oz[7]);
    float* tg = (t < 64) ? (out + O_ZT + (size_t)b * 512 + (size_t)t * 8)
                         : (out + O_ZG + (size_t)b * 512 + (size_t)(t - 64) * 8);
    *(float4*)tg       = make_float4(zq[0], zq[1], zq[2], zq[3]);
    *(float4*)(tg + 4) = make_float4(zq[4], zq[5], zq[6], zq[7]);

    __shared__ float red[128];
    red[t] = ss; __syncthreads();
    for (int s = 64; s > 0; s >>= 1) { if (t < s) red[t] += red[t + s]; __syncthreads(); }
    if (t == 0) atomicAdd(&scal[0], red[0]);
}

__global__ __launch_bounds__(256) void k_finalize(const float* __restrict__ avgp,
                                                  const float* __restrict__ scal,
                                                  float* __restrict__ out) {
    int t = threadIdx.x;
    float s = 0.f;
    for (int n = t; n < NEc; n += 256) {
        float a = avgp[n] * (1.0f / 8192.0f);
        s -= a * logf(a + 1e-5f);
    }
    __shared__ float red[256];
    red[t] = s; __syncthreads();
    for (int st = 128; st > 0; st >>= 1) { if (t < st) red[t] += red[t + st]; __syncthreads(); }
    if (t == 0) {
        float aent = red[0];
        float vq = scal[0] * (1.0f / 8388608.0f);
        float se = scal[1] * (1.0f / 8192.0f);
        out[O_VQ]  = vq;
        out[O_CM]  = 0.25f * vq;
        out[O_ENT] = 0.1f * (se - aent);
        out[O_TD]  = scal[2] * (1.0f / 8192.0f);
        out[O_GD]  = scal[3] * (1.0f / 8192.0f);
    }
}

extern "C" void kernel_launch(void* const* d_in, const int* in_sizes, int n_in,
                              void* d_out, int out_size, void* d_ws, size_t ws_size,
                              hipStream_t stream) {
    const float* z  = (const float*)d_in[0];
    const float* et = (const float*)d_in[1];
    const float* eg = (const float*)d_in[2];
    float* out = (float*)d_out;
    float* ws  = (float*)d_ws;

    _Float16* zh = (_Float16*)(ws + WS_ZH);
    _Float16* zl = (_Float16*)(ws + WS_ZL);
    _Float16* eh = (_Float16*)(ws + WS_EH);
    _Float16* el = (_Float16*)(ws + WS_EL);
    float* z2t = ws + WS_Z2T;
    float* z2g = ws + WS_Z2G;
    float* e2t = ws + WS_E2T;
    float* e2g = ws + WS_E2G;
    float* pm  = ws + WS_PM;
    float* pz  = ws + WS_PZ;
    float* ps1 = ws + WS_PS1;
    float* pdm = ws + WS_PDM;
    float* pdt = ws + WS_PDT;
    float* pdg = ws + WS_PDG;
    int*   pix = (int*)(ws + WS_PIX);
    float* lsep = ws + WS_LSE;
    int*   idxi = (int*)(ws + WS_IDX);
    float* avgp = ws + WS_AVGP;
    float* scal = ws + WS_SCAL;
    unsigned short* qm = (unsigned short*)(ws + WS_QM);

    bool storeq = (ws_size >= WS_STORE_END * sizeof(float));

    k_zero<<<(8208 + 255) / 256, 256, 0, stream>>>(avgp, 8208);  // avgp + scal contiguous
    k_norm_z<<<4096, 256, 0, stream>>>(z, zh, zl, z2t, z2g);
    k_norm_e<<<4096, 256, 0, stream>>>(et, eg, eh, el, e2t, e2g);

    dim3 gg(64, 64);
    if (storeq) {
        k_gemm<1, true><<<gg, 512, 0, stream>>>(zh, zl, eh, el, z2t, z2g, e2t, e2g,
                                                pm, pz, ps1, pdm, pdt, pdg, pix, qm, lsep, avgp);
    } else {
        k_gemm<1, false><<<gg, 512, 0, stream>>>(zh, zl, eh, el, z2t, z2g, e2t, e2g,
                                                 pm, pz, ps1, pdm, pdt, pdg, pix, qm, lsep, avgp);
    }
    k_rowreduce<<<8192, 64, 0, stream>>>(pm, pz, ps1, pdm, pdt, pdg, pix, lsep, idxi, scal, out);
    if (storeq) {
        k_colsumq<<<dim3(64, 32), 256, 0, stream>>>(qm, pm, lsep, avgp);
    } else {
        k_gemm<2, false><<<gg, 512, 0, stream>>>(zh, zl, eh, el, z2t, z2g, e2t, e2g,
                                                 pm, pz, ps1, pdm, pdt, pdg, pix, qm, lsep, avgp);
    }
    k_gather<<<8192, 128, 0, stream>>>(zh, zl, eh, el, idxi, out, scal);
    k_finalize<<<1, 256, 0, stream>>>(avgp, scal, out);
}

// Round 3
// 892.550 us; speedup vs baseline: 4.8549x; 1.3128x over previous
//
#include <hip/hip_runtime.h>
#include <cmath>

using f32x4 = __attribute__((ext_vector_type(4))) float;
using f16x8 = __attribute__((ext_vector_type(8))) _Float16;

#define SCL_H  256.0f
#define INV_HH (1.0f/65536.0f)

// ---------------- workspace layout (float units) ----------------
#define WS_ZH   ((size_t)0)
#define WS_ZL   ((size_t)4194304)
#define WS_EH   ((size_t)8388608)
#define WS_EL   ((size_t)12582912)
#define WS_Z2T  ((size_t)16777216)
#define WS_Z2G  ((size_t)16785408)
#define WS_E2T  ((size_t)16793600)
#define WS_E2G  ((size_t)16801792)
#define WS_PM   ((size_t)16809984)
#define WS_PZ   ((size_t)17334272)
#define WS_PS1  ((size_t)17858560)
#define WS_PDM  ((size_t)18382848)
#define WS_PDT  ((size_t)18907136)
#define WS_PDG  ((size_t)19431424)
#define WS_PIX  ((size_t)19955712)
#define WS_PSC  ((size_t)20480000)
#define WS_LSE  ((size_t)21004288)
#define WS_IDX  ((size_t)21012480)
#define WS_RENT ((size_t)21020672)
#define WS_RDT  ((size_t)21028864)
#define WS_RDG  ((size_t)21037056)
#define WS_GVQ  ((size_t)21045248)
#define WS_AVG4 ((size_t)21053440)
#define WS_QM   ((size_t)21118976)
#define WS_STORE_END ((size_t)54673408)

// ---------------- output layout (floats) ----------------
#define O_VQ  ((size_t)8388608)
#define O_CM  ((size_t)8388609)
#define O_ENT ((size_t)8388610)
#define O_TD  ((size_t)8388611)
#define O_GD  ((size_t)8388612)
#define O_ZT  ((size_t)8388613)
#define O_ZG  ((size_t)12582917)
#define O_IX  ((size_t)16777221)

__device__ __forceinline__ size_t tiled_off(int row, int chunk) {
    // chunk = k/8 in [0,128). layout: [rowblk][kt][slot][row&127][8]
    return (((size_t)(row >> 7) * 32 + (chunk >> 2)) * 4 + (size_t)(chunk & 3)) * 1024
           + (size_t)(row & 127) * 8;
}

__device__ __forceinline__ void gload16(const void* g, void* l) {
    __builtin_amdgcn_global_load_lds(
        (const __attribute__((address_space(1))) unsigned int*)g,
        (__attribute__((address_space(3))) unsigned int*)l, 16, 0, 0);
}

__device__ __forceinline__ f32x4 mfma16(f16x8 a, f16x8 b, f32x4 c) {
    return __builtin_amdgcn_mfma_f32_16x16x32_f16(a, b, c, 0, 0, 0);
}

__device__ __forceinline__ unsigned short f2bf(float x) {
    unsigned int u = __float_as_uint(x);
    return (unsigned short)((u + 0x7fffu + ((u >> 16) & 1u)) >> 16);
}
__device__ __forceinline__ float bf2f(unsigned short u) {
    return __uint_as_float(((unsigned int)u) << 16);
}

__global__ __launch_bounds__(256) void k_zero(float* __restrict__ p, int n) {
    int i = blockIdx.x * 256 + threadIdx.x;
    if (i < n) p[i] = 0.0f;
}

// ---- normalize z rows (halves independently); coalesced tiled writes ----
__global__ __launch_bounds__(1024) void k_norm_z(const float* __restrict__ z,
        _Float16* __restrict__ zh, _Float16* __restrict__ zl,
        float* __restrict__ z2t, float* __restrict__ z2g) {
    int t = threadIdx.x;
    int r8 = t & 7, ck = t >> 3;              // row-in-8, chunk 0..127
    int row = blockIdx.x * 8 + r8;
    const float* src = z + (size_t)row * 1024 + (size_t)ck * 8;
    float4 v0 = *(const float4*)src;
    float4 v1 = *(const float4*)(src + 4);
    float v[8] = {v0.x,v0.y,v0.z,v0.w,v1.x,v1.y,v1.z,v1.w};
    float ss = 0.f;
#pragma unroll
    for (int e = 0; e < 8; ++e) ss += v[e]*v[e];
    __shared__ float red[8*132];
    int ri = r8*132 + ck;
    red[ri] = ss; __syncthreads();
    for (int s = 32; s > 0; s >>= 1) { if ((ck & 63) < s) red[ri] += red[ri+s]; __syncthreads(); }
    float nrm = sqrtf(red[r8*132 + (ck & 64)]);
    float nv[8]; float s2 = 0.f;
#pragma unroll
    for (int e = 0; e < 8; ++e) { nv[e] = v[e]/nrm; s2 += nv[e]*nv[e]; }
    __syncthreads();
    red[ri] = s2; __syncthreads();
    for (int s = 32; s > 0; s >>= 1) { if ((ck & 63) < s) red[ri] += red[ri+s]; __syncthreads(); }
    if ((ck & 63) == 0) { if (ck & 64) z2g[row] = red[ri]; else z2t[row] = red[ri]; }
    f16x8 h8, l8;
#pragma unroll
    for (int e = 0; e < 8; ++e) {
        float xs = nv[e]*SCL_H;
        _Float16 h = (_Float16)xs; h8[e] = h;
        l8[e] = (_Float16)((xs - (float)h) * 4096.0f);
    }
    size_t off = tiled_off(row, ck);
    *(f16x8*)(zh + off) = h8;
    *(f16x8*)(zl + off) = l8;
}

// ---- normalize emb rows (text ck<64, graph ck>=64) ----
__global__ __launch_bounds__(1024) void k_norm_e(const float* __restrict__ et, const float* __restrict__ eg,
        _Float16* __restrict__ eh, _Float16* __restrict__ el,
        float* __restrict__ e2t, float* __restrict__ e2g) {
    int t = threadIdx.x;
    int r8 = t & 7, ck = t >> 3;
    int row = blockIdx.x * 8 + r8;
    const float* src = (ck < 64) ? (et + (size_t)row * 512 + (size_t)ck * 8)
                                 : (eg + (size_t)row * 512 + (size_t)(ck - 64) * 8);
    float4 v0 = *(const float4*)src;
    float4 v1 = *(const float4*)(src + 4);
    float v[8] = {v0.x,v0.y,v0.z,v0.w,v1.x,v1.y,v1.z,v1.w};
    float ss = 0.f;
#pragma unroll
    for (int e = 0; e < 8; ++e) ss += v[e]*v[e];
    __shared__ float red[8*132];
    int ri = r8*132 + ck;
    red[ri] = ss; __syncthreads();
    for (int s = 32; s > 0; s >>= 1) { if ((ck & 63) < s) red[ri] += red[ri+s]; __syncthreads(); }
    float nrm = sqrtf(red[r8*132 + (ck & 64)]);
    float nv[8]; float s2 = 0.f;
#pragma unroll
    for (int e = 0; e < 8; ++e) { nv[e] = v[e]/nrm; s2 += nv[e]*nv[e]; }
    __syncthreads();
    red[ri] = s2; __syncthreads();
    for (int s = 32; s > 0; s >>= 1) { if ((ck & 63) < s) red[ri] += red[ri+s]; __syncthreads(); }
    if ((ck & 63) == 0) { if (ck & 64) e2g[row] = red[ri]; else e2t[row] = red[ri]; }
    f16x8 h8, l8;
#pragma unroll
    for (int e = 0; e < 8; ++e) {
        float xs = nv[e]*SCL_H;
        _Float16 h = (_Float16)xs; h8[e] = h;
        l8[e] = (_Float16)((xs - (float)h) * 4096.0f);
    }
    size_t off = tiled_off(row, ck);
    *(f16x8*)(eh + off) = h8;
    *(f16x8*)(el + off) = l8;
}

// ---- MFMA distance GEMM: 128x128 tile, 8 waves 2x4, 3-buffer counted-vmcnt pipeline ----
template<int PASS, bool STOREQ>
__global__ __launch_bounds__(512, 2) void k_gemm(
    const _Float16* __restrict__ zht, const _Float16* __restrict__ zlt,
    const _Float16* __restrict__ eht, const _Float16* __restrict__ elt,
    const float* __restrict__ z2t, const float* __restrict__ z2g,
    const float* __restrict__ e2t, const float* __restrict__ e2g,
    float* __restrict__ pm, float* __restrict__ pz, float* __restrict__ ps1,
    float* __restrict__ pdm, float* __restrict__ pdt, float* __restrict__ pdg,
    int* __restrict__ pix, unsigned short* __restrict__ qm,
    const float* __restrict__ lse, float* __restrict__ avgp)
{
    const int nj = blockIdx.x, bi = blockIdx.y;
    const int t = threadIdx.x;
    const int lane = t & 63, wid = t >> 6;
    const int wave_r = wid >> 2, wave_c = wid & 3;
    const int jf = lane & 15, g = lane >> 4;

    __shared__ __align__(16) _Float16 stg[4][3][4096];   // Ah, Al, Bh, Bl — 96KB
    __shared__ float sM[128][4], sDt[128][4], sDg[128][4], sDm[128][4], sZ[128][4], sS1[128][4];
    __shared__ int   sIx[128][4];
    __shared__ float sMf[128];
    __shared__ float scol[128];

    if (PASS == 2 && t < 128) scol[t] = 0.f;

    f32x4 acct[4][2] = {};
    f32x4 accg[4][2] = {};
    f32x4 accx[4][2] = {};

    const _Float16* pa_h = zht + (size_t)bi * 131072 + (size_t)t * 8;
    const _Float16* pa_l = zlt + (size_t)bi * 131072 + (size_t)t * 8;
    const _Float16* pb_h = eht + (size_t)nj * 131072 + (size_t)t * 8;
    const _Float16* pb_l = elt + (size_t)nj * 131072 + (size_t)t * 8;

#define STAGE(KT, B) { \
        gload16(pa_h + (size_t)(KT) * 4096, &stg[0][B][t * 8]); \
        gload16(pa_l + (size_t)(KT) * 4096, &stg[1][B][t * 8]); \
        gload16(pb_h + (size_t)(KT) * 4096, &stg[2][B][t * 8]); \
        gload16(pb_l + (size_t)(KT) * 4096, &stg[3][B][t * 8]); }

    STAGE(0, 0)
    STAGE(1, 1)
    int cb = 0;
    for (int kt = 0; kt < 32; ++kt) {
        asm volatile("s_waitcnt lgkmcnt(0)" ::: "memory");
        if (kt == 31) { asm volatile("s_waitcnt vmcnt(0)" ::: "memory"); }
        else          { asm volatile("s_waitcnt vmcnt(4)" ::: "memory"); }
        __builtin_amdgcn_s_barrier();
        __builtin_amdgcn_sched_barrier(0);
        if (kt < 30) {
            int sb = cb + 2; if (sb >= 3) sb -= 3;
            STAGE(kt + 2, sb)
        }
        f16x8 ah[4], al[4], bh[2], bl[2];
#pragma unroll
        for (int fr = 0; fr < 4; ++fr) {
            int off = g * 1024 + (wave_r * 64 + fr * 16 + jf) * 8;
            ah[fr] = *(const f16x8*)&stg[0][cb][off];
            al[fr] = *(const f16x8*)&stg[1][cb][off];
        }
#pragma unroll
        for (int fc = 0; fc < 2; ++fc) {
            int off = g * 1024 + (wave_c * 32 + fc * 16 + jf) * 8;
            bh[fc] = *(const f16x8*)&stg[2][cb][off];
            bl[fc] = *(const f16x8*)&stg[3][cb][off];
        }
        if (kt < 16) {
#pragma unroll
            for (int fr = 0; fr < 4; ++fr)
#pragma unroll
            for (int fc = 0; fc < 2; ++fc) {
                acct[fr][fc] = mfma16(ah[fr], bh[fc], acct[fr][fc]);
                accx[fr][fc] = mfma16(ah[fr], bl[fc], accx[fr][fc]);
                accx[fr][fc] = mfma16(al[fr], bh[fc], accx[fr][fc]);
            }
        } else {
#pragma unroll
            for (int fr = 0; fr < 4; ++fr)
#pragma unroll
            for (int fc = 0; fc < 2; ++fc) {
                accg[fr][fc] = mfma16(ah[fr], bh[fc], accg[fr][fc]);
                accx[fr][fc] = mfma16(ah[fr], bl[fc], accx[fr][fc]);
                accx[fr][fc] = mfma16(al[fr], bh[fc], accx[fr][fc]);
            }
        }
        cb = (cb == 2) ? 0 : cb + 1;
    }
#undef STAGE

    const int colbase = nj * 128 + wave_c * 32;
    float e2tc[2], e2gc[2];
#pragma unroll
    for (int fc = 0; fc < 2; ++fc) {
        e2tc[fc] = e2t[colbase + fc * 16 + jf];
        e2gc[fc] = e2g[colbase + fc * 16 + jf];
    }

    if constexpr (PASS == 1) {
        unsigned short* sQ = (unsigned short*)stg;   // 32KB overlay, staging is dead now
        // stage 1: per-row max / dmin / dt2 / dg2 over this wave's 32 cols; keep l in acct
#pragma unroll
        for (int fr = 0; fr < 4; ++fr) {
#pragma unroll
            for (int reg = 0; reg < 4; ++reg) {
                int rl = wave_r * 64 + fr * 16 + g * 4 + reg;
                int i  = bi * 128 + rl;
                float z2ti = z2t[i], z2gi = z2g[i];
                float mrow = -3.0e38f, dmin = 3.0e38f, dt2 = 0.f, dg2 = 0.f;
                int dix = 0;
#pragma unroll
                for (int fc = 0; fc < 2; ++fc) {
                    float ht = acct[fr][fc][reg], hg = accg[fr][fc][reg], xx = accx[fr][fc][reg];
                    float dta = z2ti + e2tc[fc] - ht * (2.0f * INV_HH);
                    float dga = z2gi + e2gc[fc] - hg * (2.0f * INV_HH);
                    float d   = (z2ti + z2gi) + (e2tc[fc] + e2gc[fc])
                              - 2.0f * INV_HH * (ht + hg + xx * (1.0f / 4096.0f));
                    float lv  = -100.0f * d;
                    acct[fr][fc][reg] = lv;
                    dt2 += dta * dta; dg2 += dga * dga;
                    int j = colbase + fc * 16 + jf;
                    if (d < dmin) { dmin = d; dix = j; }
                    mrow = fmaxf(mrow, lv);
                }
#pragma unroll
                for (int s = 1; s < 16; s <<= 1) {
                    mrow = fmaxf(mrow, __shfl_xor(mrow, s));
                    dt2 += __shfl_xor(dt2, s);
                    dg2 += __shfl_xor(dg2, s);
                    float ov = __shfl_xor(dmin, s); int oi = __shfl_xor(dix, s);
                    if (ov < dmin || (ov == dmin && oi < dix)) { dmin = ov; dix = oi; }
                }
                if (jf == 0) {
                    sM[rl][wave_c] = mrow; sDt[rl][wave_c] = dt2; sDg[rl][wave_c] = dg2;
                    sDm[rl][wave_c] = dmin; sIx[rl][wave_c] = dix;
                }
            }
        }
        __syncthreads();
        if (t < 128) sMf[t] = fmaxf(fmaxf(sM[t][0], sM[t][1]), fmaxf(sM[t][2], sM[t][3]));
        __syncthreads();
        // stage 2: Z, S1 vs block max; q into LDS
#pragma unroll
        for (int fr = 0; fr < 4; ++fr) {
#pragma unroll
            for (int reg = 0; reg < 4; ++reg) {
                int rl = wave_r * 64 + fr * 16 + g * 4 + reg;
                float M = sMf[rl];
                float Z = 0.f, S1 = 0.f;
#pragma unroll
                for (int fc = 0; fc < 2; ++fc) {
                    float lv = acct[fr][fc][reg];
                    float e  = expf(lv - M);
                    Z += e; S1 += e * lv;
                    if constexpr (STOREQ) sQ[rl * 128 + wave_c * 32 + fc * 16 + jf] = f2bf(e);
                }
#pragma unroll
                for (int s = 1; s < 16; s <<= 1) {
                    Z  += __shfl_xor(Z, s);
                    S1 += __shfl_xor(S1, s);
                }
                if (jf == 0) { sZ[rl][wave_c] = Z; sS1[rl][wave_c] = S1; }
            }
        }
        __syncthreads();
        if (t < 128) {
            float M = sMf[t];
            float Z = sZ[t][0] + sZ[t][1] + sZ[t][2] + sZ[t][3];
            float S1 = sS1[t][0] + sS1[t][1] + sS1[t][2] + sS1[t][3];
            float dt2 = sDt[t][0] + sDt[t][1] + sDt[t][2] + sDt[t][3];
            float dg2 = sDg[t][0] + sDg[t][1] + sDg[t][2] + sDg[t][3];
            float dmin = sDm[t][0]; int dix = sIx[t][0];
#pragma unroll
            for (int w = 1; w < 4; ++w) {
                float ov = sDm[t][w]; int oi = sIx[t][w];
                if (ov < dmin || (ov == dmin && oi < dix)) { dmin = ov; dix = oi; }
            }
            size_t pb = (size_t)(bi * 128 + t) * 64 + nj;
            pm[pb] = M; pz[pb] = Z; ps1[pb] = S1;
            pdm[pb] = dmin; pdt[pb] = dt2; pdg[pb] = dg2; pix[pb] = dix;
        }
        if constexpr (STOREQ) {
            // coalesced qm write: 128 rows x 256B
#pragma unroll
            for (int p = 0; p < 2; ++p) {
                int idx = p * 512 + t;
                int row = idx >> 3, seg = idx & 7;
                const uint4* s4 = (const uint4*)(sQ + row * 128 + seg * 16);
                uint4 q0 = s4[0], q1 = s4[1];
                uint4* d4 = (uint4*)(qm + (size_t)(bi * 128 + row) * 8192 + nj * 128 + seg * 16);
                d4[0] = q0; d4[1] = q1;
            }
        }
    } else {
        // PASS 2 fallback: recompute p = exp(l - lse), column sums
        float cs0 = 0.f, cs1 = 0.f;
#pragma unroll
        for (int fr = 0; fr < 4; ++fr) {
#pragma unroll
            for (int reg = 0; reg < 4; ++reg) {
                int rl = wave_r * 64 + fr * 16 + g * 4 + reg;
                int i  = bi * 128 + rl;
                float z2ti = z2t[i], z2gi = z2g[i];
                float lsei = lse[i];
#pragma unroll
                for (int fc = 0; fc < 2; ++fc) {
                    float ht = acct[fr][fc][reg], hg = accg[fr][fc][reg], xx = accx[fr][fc][reg];
                    float d = (z2ti + z2gi) + (e2tc[fc] + e2gc[fc])
                            - 2.0f * INV_HH * (ht + hg + xx * (1.0f / 4096.0f));
                    float lv = -100.0f * d;
                    float p = expf(lv - lsei);
                    if (fc == 0) cs0 += p; else cs1 += p;
                }
            }
        }
        cs0 += __shfl_xor(cs0, 16); cs0 += __shfl_xor(cs0, 32);
        cs1 += __shfl_xor(cs1, 16); cs1 += __shfl_xor(cs1, 32);
        if (g == 0) {
            atomicAdd(&scol[wave_c * 32 + jf], cs0);
            atomicAdd(&scol[wave_c * 32 + 16 + jf], cs1);
        }
        __syncthreads();
        if (t < 128) atomicAdd(&avgp[nj * 128 + t], scol[t]);
    }
}

// ---- merge 64 per-colblock partials per row; write pscale; NO global atomics ----
__global__ __launch_bounds__(256) void k_rowreduce(
    const float* __restrict__ pm, const float* __restrict__ pz, const float* __restrict__ ps1,
    const float* __restrict__ pdm, const float* __restrict__ pdt, const float* __restrict__ pdg,
    const int* __restrict__ pix,
    float* __restrict__ pscale, float* __restrict__ lse, int* __restrict__ idxo,
    float* __restrict__ rent, float* __restrict__ rdt, float* __restrict__ rdg,
    float* __restrict__ out)
{
    int b = blockIdx.x * 4 + (threadIdx.x >> 6);
    int l = threadIdx.x & 63;
    size_t pb = (size_t)b * 64 + l;
    float m0 = pm[pb];
    float m = m0;
#pragma unroll
    for (int s = 1; s < 64; s <<= 1) m = fmaxf(m, __shfl_xor(m, s));
    float sc = expf(m0 - m);
    float Z = pz[pb] * sc, S1 = ps1[pb] * sc;
    float dt2 = pdt[pb], dg2 = pdg[pb];
    float dmin = pdm[pb]; int dix = pix[pb];
#pragma unroll
    for (int s = 1; s < 64; s <<= 1) {
        Z += __shfl_xor(Z, s); S1 += __shfl_xor(S1, s);
        dt2 += __shfl_xor(dt2, s); dg2 += __shfl_xor(dg2, s);
        float ov = __shfl_xor(dmin, s); int oi = __shfl_xor(dix, s);
        if (ov < dmin || (ov == dmin && oi < dix)) { dmin = ov; dix = oi; }
    }
    float lseb = m + logf(Z);
    pscale[pb] = expf(m0 - lseb);
    if (l == 0) {
        lse[b] = lseb; idxo[b] = dix;
        out[O_IX + b] = (float)dix;
        rent[b] = lseb - S1 / Z;
        rdt[b] = dt2; rdg[b] = dg2;
    }
}

// ---- stored-q column sums, atomic-free: avg4[rb][n] = sum over 1024 rows ----
__global__ __launch_bounds__(256) void k_colsum(const unsigned short* __restrict__ qm,
                                                const float* __restrict__ pscale,
                                                float* __restrict__ avg4) {
    int cc = blockIdx.x, rb = blockIdx.y, t = threadIdx.x;
    int cp = t & 63, rg = t >> 6;
    float a0 = 0.f, a1 = 0.f;
    const unsigned short* qb = qm + (size_t)cc * 128 + (size_t)cp * 2;
#pragma unroll 4
    for (int rr = rg; rr < 1024; rr += 4) {
        int r = rb * 1024 + rr;
        float s = pscale[(size_t)r * 64 + cc];
        unsigned int q = *(const unsigned int*)(qb + (size_t)r * 8192);
        a0 += bf2f((unsigned short)(q & 0xffffu)) * s;
        a1 += bf2f((unsigned short)(q >> 16)) * s;
    }
    __shared__ float red[512];
    red[rg * 128 + cp * 2] = a0; red[rg * 128 + cp * 2 + 1] = a1;
    __syncthreads();
    if (rg == 0) {
        float s0 = red[cp*2]   + red[128+cp*2]   + red[256+cp*2]   + red[384+cp*2];
        float s1 = red[cp*2+1] + red[128+cp*2+1] + red[256+cp*2+1] + red[384+cp*2+1];
        avg4[(size_t)rb * 8192 + cc * 128 + cp * 2]     = s0;
        avg4[(size_t)rb * 8192 + cc * 128 + cp * 2 + 1] = s1;
    }
}

// ---- gather z_q outputs + per-row vq sums (no atomics) ----
__global__ __launch_bounds__(1024) void k_gather(
    const _Float16* __restrict__ zh, const _Float16* __restrict__ zl,
    const _Float16* __restrict__ eh, const _Float16* __restrict__ el,
    const int* __restrict__ idxi, float* __restrict__ out, float* __restrict__ gvq)
{
    int t = threadIdx.x;
    int r8 = t & 7, ck = t >> 3;
    int b = blockIdx.x * 8 + r8;
    int idx = idxi[b];
    size_t zo = tiled_off(b, ck), eo = tiled_off(idx, ck);
    f16x8 zh8 = *(const f16x8*)(zh + zo);
    f16x8 zl8 = *(const f16x8*)(zl + zo);
    f16x8 eh8 = *(const f16x8*)(eh + eo);
    f16x8 el8 = *(const f16x8*)(el + eo);
    float ss = 0.f; float oz[8], zq[8];
#pragma unroll
    for (int e = 0; e < 8; ++e) {
        float zn = ((float)zh8[e] + (float)zl8[e] * (1.0f / 4096.0f)) * (1.0f / SCL_H);
        float eq = ((float)eh8[e] + (float)el8[e] * (1.0f / 4096.0f)) * (1.0f / SCL_H);
        float df = eq - zn;
        zq[e] = eq; oz[e] = zn + df; ss += df * df;
    }
    float* dst = out + (size_t)b * 1024 + (size_t)ck * 8;
    *(float4*)dst       = make_float4(oz[0], oz[1], oz[2], oz[3]);
    *(float4*)(dst + 4) = make_float4(oz[4], oz[5], oz[6], oz[7]);
    float* tg = (ck < 64) ? (out + O_ZT + (size_t)b * 512 + (size_t)ck * 8)
                          : (out + O_ZG + (size_t)b * 512 + (size_t)(ck - 64) * 8);
    *(float4*)tg       = make_float4(zq[0], zq[1], zq[2], zq[3]);
    *(float4*)(tg + 4) = make_float4(zq[4], zq[5], zq[6], zq[7]);
    __shared__ float red[8*132];
    int ri = r8 * 132 + ck;
    red[ri] = ss; __syncthreads();
    for (int s = 64; s > 0; s >>= 1) { if (ck < s) red[ri] += red[ri + s]; __syncthreads(); }
    if (ck == 0) gvq[b] = red[ri];
}

__global__ __launch_bounds__(256) void k_finalize(const float* __restrict__ avg4,
        const float* __restrict__ rent, const float* __restrict__ rdt,
        const float* __restrict__ rdg, const float* __restrict__ gvq,
        float* __restrict__ out) {
    int t = threadIdx.x;
    float ent = 0.f, se = 0.f, dt = 0.f, dg = 0.f, vq = 0.f;
    for (int n = t; n < 8192; n += 256) {
        float a = 0.f;
#pragma unroll
        for (int k = 0; k < 8; ++k) a += avg4[(size_t)k * 8192 + n];
        a *= (1.0f / 8192.0f);
        ent -= a * logf(a + 1e-5f);
        se += rent[n]; dt += rdt[n]; dg += rdg[n]; vq += gvq[n];
    }
    __shared__ float red[256];
#define RED(x) { red[t] = x; __syncthreads(); \
    for (int s = 128; s > 0; s >>= 1) { if (t < s) red[t] += red[t + s]; __syncthreads(); } \
    x = red[0]; __syncthreads(); }
    RED(ent) RED(se) RED(dt) RED(dg) RED(vq)
#undef RED
    if (t == 0) {
        float vqm = vq * (1.0f / 8388608.0f);
        out[O_VQ]  = vqm;
        out[O_CM]  = 0.25f * vqm;
        out[O_ENT] = 0.1f * (se * (1.0f / 8192.0f) - ent);
        out[O_TD]  = dt * (1.0f / 8192.0f);
        out[O_GD]  = dg * (1.0f / 8192.0f);
    }
}

extern "C" void kernel_launch(void* const* d_in, const int* in_sizes, int n_in,
                              void* d_out, int out_size, void* d_ws, size_t ws_size,
                              hipStream_t stream) {
    const float* z  = (const float*)d_in[0];
    const float* et = (const float*)d_in[1];
    const float* eg = (const float*)d_in[2];
    float* out = (float*)d_out;
    float* ws  = (float*)d_ws;

    _Float16* zh = (_Float16*)(ws + WS_ZH);
    _Float16* zl = (_Float16*)(ws + WS_ZL);
    _Float16* eh = (_Float16*)(ws + WS_EH);
    _Float16* el = (_Float16*)(ws + WS_EL);
    float* z2t = ws + WS_Z2T;
    float* z2g = ws + WS_Z2G;
    float* e2t = ws + WS_E2T;
    float* e2g = ws + WS_E2G;
    float* pm  = ws + WS_PM;
    float* pz  = ws + WS_PZ;
    float* ps1 = ws + WS_PS1;
    float* pdm = ws + WS_PDM;
    float* pdt = ws + WS_PDT;
    float* pdg = ws + WS_PDG;
    int*   pix = (int*)(ws + WS_PIX);
    float* psc = ws + WS_PSC;
    float* lsep = ws + WS_LSE;
    int*   idxi = (int*)(ws + WS_IDX);
    float* rent = ws + WS_RENT;
    float* rdt  = ws + WS_RDT;
    float* rdg  = ws + WS_RDG;
    float* gvq  = ws + WS_GVQ;
    float* avg4 = ws + WS_AVG4;
    unsigned short* qm = (unsigned short*)(ws + WS_QM);

    bool storeq = (ws_size >= WS_STORE_END * sizeof(float));

    k_norm_z<<<1024, 1024, 0, stream>>>(z, zh, zl, z2t, z2g);
    k_norm_e<<<1024, 1024, 0, stream>>>(et, eg, eh, el, e2t, e2g);

    dim3 gg(64, 64);
    if (storeq) {
        k_gemm<1, true><<<gg, 512, 0, stream>>>(zh, zl, eh, el, z2t, z2g, e2t, e2g,
                                                pm, pz, ps1, pdm, pdt, pdg, pix, qm, lsep, avg4);
    } else {
        k_gemm<1, false><<<gg, 512, 0, stream>>>(zh, zl, eh, el, z2t, z2g, e2t, e2g,
                                                 pm, pz, ps1, pdm, pdt, pdg, pix, qm, lsep, avg4);
    }
    k_rowreduce<<<2048, 256, 0, stream>>>(pm, pz, ps1, pdm, pdt, pdg, pix,
                                          psc, lsep, idxi, rent, rdt, rdg, out);
    if (storeq) {
        k_colsum<<<dim3(64, 8), 256, 0, stream>>>(qm, psc, avg4);
    } else {
        k_zero<<<256, 256, 0, stream>>>(avg4, 65536);
        k_gemm<2, false><<<gg, 512, 0, stream>>>(zh, zl, eh, el, z2t, z2g, e2t, e2g,
                                                 pm, pz, ps1, pdm, pdt, pdg, pix, qm, lsep, avg4);
    }
    k_gather<<<1024, 1024, 0, stream>>>(zh, zl, eh, el, idxi, out, gvq);
    k_finalize<<<1, 256, 0, stream>>>(avg4, rent, rdt, rdg, gvq, out);
}

// Round 4
// 890.983 us; speedup vs baseline: 4.8634x; 1.0018x over previous
//
#include <hip/hip_runtime.h>
#include <cmath>

using f32x4 = __attribute__((ext_vector_type(4))) float;
using f16x8 = __attribute__((ext_vector_type(8))) _Float16;

#define SCL_H  256.0f
#define INV_HH (1.0f/65536.0f)

// ---------------- workspace layout (float units) ----------------
#define WS_ZH   ((size_t)0)
#define WS_ZL   ((size_t)4194304)
#define WS_EH   ((size_t)8388608)
#define WS_EL   ((size_t)12582912)
#define WS_Z2T  ((size_t)16777216)
#define WS_Z2G  ((size_t)16785408)
#define WS_E2T  ((size_t)16793600)
#define WS_E2G  ((size_t)16801792)
#define WS_PM   ((size_t)16809984)
#define WS_PZ   ((size_t)17334272)
#define WS_PS1  ((size_t)17858560)
#define WS_PDM  ((size_t)18382848)
#define WS_PDT  ((size_t)18907136)
#define WS_PDG  ((size_t)19431424)
#define WS_PIX  ((size_t)19955712)
#define WS_PSC  ((size_t)20480000)
#define WS_LSE  ((size_t)21004288)
#define WS_IDX  ((size_t)21012480)
#define WS_RENT ((size_t)21020672)
#define WS_RDT  ((size_t)21028864)
#define WS_RDG  ((size_t)21037056)
#define WS_GVQ  ((size_t)21045248)
#define WS_AVG4 ((size_t)21053440)
#define WS_QM   ((size_t)21118976)
#define WS_STORE_END ((size_t)54673408)

// ---------------- output layout (floats) ----------------
#define O_VQ  ((size_t)8388608)
#define O_CM  ((size_t)8388609)
#define O_ENT ((size_t)8388610)
#define O_TD  ((size_t)8388611)
#define O_GD  ((size_t)8388612)
#define O_ZT  ((size_t)8388613)
#define O_ZG  ((size_t)12582917)
#define O_IX  ((size_t)16777221)

__device__ __forceinline__ size_t tiled_off(int row, int chunk) {
    // chunk = k/8 in [0,128). layout: [rowblk][kt][slot][row&127][8]
    return (((size_t)(row >> 7) * 32 + (chunk >> 2)) * 4 + (size_t)(chunk & 3)) * 1024
           + (size_t)(row & 127) * 8;
}

__device__ __forceinline__ void gload16(const void* g, void* l) {
    __builtin_amdgcn_global_load_lds(
        (const __attribute__((address_space(1))) unsigned int*)g,
        (__attribute__((address_space(3))) unsigned int*)l, 16, 0, 0);
}

__device__ __forceinline__ f32x4 mfma16(f16x8 a, f16x8 b, f32x4 c) {
    return __builtin_amdgcn_mfma_f32_16x16x32_f16(a, b, c, 0, 0, 0);
}

__device__ __forceinline__ unsigned short f2bf(float x) {
    unsigned int u = __float_as_uint(x);
    return (unsigned short)((u + 0x7fffu + ((u >> 16) & 1u)) >> 16);
}
__device__ __forceinline__ float bf2f(unsigned short u) {
    return __uint_as_float(((unsigned int)u) << 16);
}

__global__ __launch_bounds__(256) void k_zero(float* __restrict__ p, int n) {
    int i = blockIdx.x * 256 + threadIdx.x;
    if (i < n) p[i] = 0.0f;
}

// ---- normalize z rows (halves independently); coalesced tiled writes ----
__global__ __launch_bounds__(1024) void k_norm_z(const float* __restrict__ z,
        _Float16* __restrict__ zh, _Float16* __restrict__ zl,
        float* __restrict__ z2t, float* __restrict__ z2g) {
    int t = threadIdx.x;
    int r8 = t & 7, ck = t >> 3;              // row-in-8, chunk 0..127
    int row = blockIdx.x * 8 + r8;
    const float* src = z + (size_t)row * 1024 + (size_t)ck * 8;
    float4 v0 = *(const float4*)src;
    float4 v1 = *(const float4*)(src + 4);
    float v[8] = {v0.x,v0.y,v0.z,v0.w,v1.x,v1.y,v1.z,v1.w};
    float ss = 0.f;
#pragma unroll
    for (int e = 0; e < 8; ++e) ss += v[e]*v[e];
    __shared__ float red[8*132];
    int ri = r8*132 + ck;
    red[ri] = ss; __syncthreads();
    for (int s = 32; s > 0; s >>= 1) { if ((ck & 63) < s) red[ri] += red[ri+s]; __syncthreads(); }
    float nrm = sqrtf(red[r8*132 + (ck & 64)]);
    float nv[8]; float s2 = 0.f;
#pragma unroll
    for (int e = 0; e < 8; ++e) { nv[e] = v[e]/nrm; s2 += nv[e]*nv[e]; }
    __syncthreads();
    red[ri] = s2; __syncthreads();
    for (int s = 32; s > 0; s >>= 1) { if ((ck & 63) < s) red[ri] += red[ri+s]; __syncthreads(); }
    if ((ck & 63) == 0) { if (ck & 64) z2g[row] = red[ri]; else z2t[row] = red[ri]; }
    f16x8 h8, l8;
#pragma unroll
    for (int e = 0; e < 8; ++e) {
        float xs = nv[e]*SCL_H;
        _Float16 h = (_Float16)xs; h8[e] = h;
        l8[e] = (_Float16)((xs - (float)h) * 4096.0f);
    }
    size_t off = tiled_off(row, ck);
    *(f16x8*)(zh + off) = h8;
    *(f16x8*)(zl + off) = l8;
}

// ---- normalize emb rows (text ck<64, graph ck>=64) ----
__global__ __launch_bounds__(1024) void k_norm_e(const float* __restrict__ et, const float* __restrict__ eg,
        _Float16* __restrict__ eh, _Float16* __restrict__ el,
        float* __restrict__ e2t, float* __restrict__ e2g) {
    int t = threadIdx.x;
    int r8 = t & 7, ck = t >> 3;
    int row = blockIdx.x * 8 + r8;
    const float* src = (ck < 64) ? (et + (size_t)row * 512 + (size_t)ck * 8)
                                 : (eg + (size_t)row * 512 + (size_t)(ck - 64) * 8);
    float4 v0 = *(const float4*)src;
    float4 v1 = *(const float4*)(src + 4);
    float v[8] = {v0.x,v0.y,v0.z,v0.w,v1.x,v1.y,v1.z,v1.w};
    float ss = 0.f;
#pragma unroll
    for (int e = 0; e < 8; ++e) ss += v[e]*v[e];
    __shared__ float red[8*132];
    int ri = r8*132 + ck;
    red[ri] = ss; __syncthreads();
    for (int s = 32; s > 0; s >>= 1) { if ((ck & 63) < s) red[ri] += red[ri+s]; __syncthreads(); }
    float nrm = sqrtf(red[r8*132 + (ck & 64)]);
    float nv[8]; float s2 = 0.f;
#pragma unroll
    for (int e = 0; e < 8; ++e) { nv[e] = v[e]/nrm; s2 += nv[e]*nv[e]; }
    __syncthreads();
    red[ri] = s2; __syncthreads();
    for (int s = 32; s > 0; s >>= 1) { if ((ck & 63) < s) red[ri] += red[ri+s]; __syncthreads(); }
    if ((ck & 63) == 0) { if (ck & 64) e2g[row] = red[ri]; else e2t[row] = red[ri]; }
    f16x8 h8, l8;
#pragma unroll
    for (int e = 0; e < 8; ++e) {
        float xs = nv[e]*SCL_H;
        _Float16 h = (_Float16)xs; h8[e] = h;
        l8[e] = (_Float16)((xs - (float)h) * 4096.0f);
    }
    size_t off = tiled_off(row, ck);
    *(f16x8*)(eh + off) = h8;
    *(f16x8*)(el + off) = l8;
}

// ---- MFMA distance GEMM: 128x128 tile, 8 waves 2x4, 3-buffer counted-vmcnt pipeline ----
template<int PASS, bool STOREQ>
__global__ __launch_bounds__(512, 2) void k_gemm(
    const _Float16* __restrict__ zht, const _Float16* __restrict__ zlt,
    const _Float16* __restrict__ eht, const _Float16* __restrict__ elt,
    const float* __restrict__ z2t, const float* __restrict__ z2g,
    const float* __restrict__ e2t, const float* __restrict__ e2g,
    float* __restrict__ pm, float* __restrict__ pz, float* __restrict__ ps1,
    float* __restrict__ pdm, float* __restrict__ pdt, float* __restrict__ pdg,
    int* __restrict__ pix, unsigned short* __restrict__ qm,
    const float* __restrict__ lse, float* __restrict__ avgp)
{
    const int nj = blockIdx.x, bi = blockIdx.y;
    const int t = threadIdx.x;
    const int lane = t & 63, wid = t >> 6;
    const int wave_r = wid >> 2, wave_c = wid & 3;
    const int jf = lane & 15, g = lane >> 4;

    __shared__ __align__(16) _Float16 stg[4][3][4096];   // Ah, Al, Bh, Bl — 96KB
    __shared__ float sM[128][4], sDt[128][4], sDg[128][4], sDm[128][4], sZ[128][4], sS1[128][4];
    __shared__ int   sIx[128][4];
    __shared__ float sMf[128];
    __shared__ float scol[128];

    if (PASS == 2 && t < 128) scol[t] = 0.f;

    f32x4 acct[4][2] = {};
    f32x4 accg[4][2] = {};
    f32x4 accx[4][2] = {};

    const _Float16* pa_h = zht + (size_t)bi * 131072 + (size_t)t * 8;
    const _Float16* pa_l = zlt + (size_t)bi * 131072 + (size_t)t * 8;
    const _Float16* pb_h = eht + (size_t)nj * 131072 + (size_t)t * 8;
    const _Float16* pb_l = elt + (size_t)nj * 131072 + (size_t)t * 8;

#define STAGE(KT, B) { \
        gload16(pa_h + (size_t)(KT) * 4096, &stg[0][B][t * 8]); \
        gload16(pa_l + (size_t)(KT) * 4096, &stg[1][B][t * 8]); \
        gload16(pb_h + (size_t)(KT) * 4096, &stg[2][B][t * 8]); \
        gload16(pb_l + (size_t)(KT) * 4096, &stg[3][B][t * 8]); }

    STAGE(0, 0)
    STAGE(1, 1)
    int cb = 0;
    for (int kt = 0; kt < 32; ++kt) {
        asm volatile("s_waitcnt lgkmcnt(0)" ::: "memory");
        if (kt == 31) { asm volatile("s_waitcnt vmcnt(0)" ::: "memory"); }
        else          { asm volatile("s_waitcnt vmcnt(4)" ::: "memory"); }
        __builtin_amdgcn_s_barrier();
        __builtin_amdgcn_sched_barrier(0);
        if (kt < 30) {
            int sb = cb + 2; if (sb >= 3) sb -= 3;
            STAGE(kt + 2, sb)
        }
        f16x8 ah[4], al[4], bh[2], bl[2];
#pragma unroll
        for (int fr = 0; fr < 4; ++fr) {
            int off = g * 1024 + (wave_r * 64 + fr * 16 + jf) * 8;
            ah[fr] = *(const f16x8*)&stg[0][cb][off];
            al[fr] = *(const f16x8*)&stg[1][cb][off];
        }
#pragma unroll
        for (int fc = 0; fc < 2; ++fc) {
            int off = g * 1024 + (wave_c * 32 + fc * 16 + jf) * 8;
            bh[fc] = *(const f16x8*)&stg[2][cb][off];
            bl[fc] = *(const f16x8*)&stg[3][cb][off];
        }
        if (kt < 16) {
#pragma unroll
            for (int fr = 0; fr < 4; ++fr)
#pragma unroll
            for (int fc = 0; fc < 2; ++fc) {
                acct[fr][fc] = mfma16(ah[fr], bh[fc], acct[fr][fc]);
                accx[fr][fc] = mfma16(ah[fr], bl[fc], accx[fr][fc]);
                accx[fr][fc] = mfma16(al[fr], bh[fc], accx[fr][fc]);
            }
        } else {
#pragma unroll
            for (int fr = 0; fr < 4; ++fr)
#pragma unroll
            for (int fc = 0; fc < 2; ++fc) {
                accg[fr][fc] = mfma16(ah[fr], bh[fc], accg[fr][fc]);
                accx[fr][fc] = mfma16(ah[fr], bl[fc], accx[fr][fc]);
                accx[fr][fc] = mfma16(al[fr], bh[fc], accx[fr][fc]);
            }
        }
        cb = (cb == 2) ? 0 : cb + 1;
    }
#undef STAGE

    const int colbase = nj * 128 + wave_c * 32;
    float e2tc[2], e2gc[2];
#pragma unroll
    for (int fc = 0; fc < 2; ++fc) {
        e2tc[fc] = e2t[colbase + fc * 16 + jf];
        e2gc[fc] = e2g[colbase + fc * 16 + jf];
    }

    if constexpr (PASS == 1) {
        unsigned short* sQ = (unsigned short*)stg;   // 32KB overlay, staging is dead now
        // stage 1: per-row max / dmin / dt2 / dg2 over this wave's 32 cols; keep l in acct
#pragma unroll
        for (int fr = 0; fr < 4; ++fr) {
#pragma unroll
            for (int reg = 0; reg < 4; ++reg) {
                int rl = wave_r * 64 + fr * 16 + g * 4 + reg;
                int i  = bi * 128 + rl;
                float z2ti = z2t[i], z2gi = z2g[i];
                float mrow = -3.0e38f, dmin = 3.0e38f, dt2 = 0.f, dg2 = 0.f;
                int dix = 0;
#pragma unroll
                for (int fc = 0; fc < 2; ++fc) {
                    float ht = acct[fr][fc][reg], hg = accg[fr][fc][reg], xx = accx[fr][fc][reg];
                    float dta = z2ti + e2tc[fc] - ht * (2.0f * INV_HH);
                    float dga = z2gi + e2gc[fc] - hg * (2.0f * INV_HH);
                    float d   = (z2ti + z2gi) + (e2tc[fc] + e2gc[fc])
                              - 2.0f * INV_HH * (ht + hg + xx * (1.0f / 4096.0f));
                    float lv  = -100.0f * d;
                    acct[fr][fc][reg] = lv;
                    dt2 += dta * dta; dg2 += dga * dga;
                    int j = colbase + fc * 16 + jf;
                    if (d < dmin) { dmin = d; dix = j; }
                    mrow = fmaxf(mrow, lv);
                }
#pragma unroll
                for (int s = 1; s < 16; s <<= 1) {
                    mrow = fmaxf(mrow, __shfl_xor(mrow, s));
                    dt2 += __shfl_xor(dt2, s);
                    dg2 += __shfl_xor(dg2, s);
                    float ov = __shfl_xor(dmin, s); int oi = __shfl_xor(dix, s);
                    if (ov < dmin || (ov == dmin && oi < dix)) { dmin = ov; dix = oi; }
                }
                if (jf == 0) {
                    sM[rl][wave_c] = mrow; sDt[rl][wave_c] = dt2; sDg[rl][wave_c] = dg2;
                    sDm[rl][wave_c] = dmin; sIx[rl][wave_c] = dix;
                }
            }
        }
        __syncthreads();
        if (t < 128) sMf[t] = fmaxf(fmaxf(sM[t][0], sM[t][1]), fmaxf(sM[t][2], sM[t][3]));
        __syncthreads();
        // stage 2: Z, S1 vs block max; q into LDS
#pragma unroll
        for (int fr = 0; fr < 4; ++fr) {
#pragma unroll
            for (int reg = 0; reg < 4; ++reg) {
                int rl = wave_r * 64 + fr * 16 + g * 4 + reg;
                float M = sMf[rl];
                float Z = 0.f, S1 = 0.f;
#pragma unroll
                for (int fc = 0; fc < 2; ++fc) {
                    float lv = acct[fr][fc][reg];
                    float e  = expf(lv - M);
                    Z += e; S1 += e * lv;
                    if constexpr (STOREQ) sQ[rl * 128 + wave_c * 32 + fc * 16 + jf] = f2bf(e);
                }
#pragma unroll
                for (int s = 1; s < 16; s <<= 1) {
                    Z  += __shfl_xor(Z, s);
                    S1 += __shfl_xor(S1, s);
                }
                if (jf == 0) { sZ[rl][wave_c] = Z; sS1[rl][wave_c] = S1; }
            }
        }
        __syncthreads();
        if (t < 128) {
            float M = sMf[t];
            float Z = sZ[t][0] + sZ[t][1] + sZ[t][2] + sZ[t][3];
            float S1 = sS1[t][0] + sS1[t][1] + sS1[t][2] + sS1[t][3];
            float dt2 = sDt[t][0] + sDt[t][1] + sDt[t][2] + sDt[t][3];
            float dg2 = sDg[t][0] + sDg[t][1] + sDg[t][2] + sDg[t][3];
            float dmin = sDm[t][0]; int dix = sIx[t][0];
#pragma unroll
            for (int w = 1; w < 4; ++w) {
                float ov = sDm[t][w]; int oi = sIx[t][w];
                if (ov < dmin || (ov == dmin && oi < dix)) { dmin = ov; dix = oi; }
            }
            size_t pb = (size_t)(bi * 128 + t) * 64 + nj;
            pm[pb] = M; pz[pb] = Z; ps1[pb] = S1;
            pdm[pb] = dmin; pdt[pb] = dt2; pdg[pb] = dg2; pix[pb] = dix;
        }
        if constexpr (STOREQ) {
            // coalesced qm write: 128 rows x 256B
#pragma unroll
            for (int p = 0; p < 2; ++p) {
                int idx = p * 512 + t;
                int row = idx >> 3, seg = idx & 7;
                const uint4* s4 = (const uint4*)(sQ + row * 128 + seg * 16);
                uint4 q0 = s4[0], q1 = s4[1];
                uint4* d4 = (uint4*)(qm + (size_t)(bi * 128 + row) * 8192 + nj * 128 + seg * 16);
                d4[0] = q0; d4[1] = q1;
            }
        }
    } else {
        // PASS 2 fallback: recompute p = exp(l - lse), column sums
        float cs0 = 0.f, cs1 = 0.f;
#pragma unroll
        for (int fr = 0; fr < 4; ++fr) {
#pragma unroll
            for (int reg = 0; reg < 4; ++reg) {
                int rl = wave_r * 64 + fr * 16 + g * 4 + reg;
                int i  = bi * 128 + rl;
                float z2ti = z2t[i], z2gi = z2g[i];
                float lsei = lse[i];
#pragma unroll
                for (int fc = 0; fc < 2; ++fc) {
                    float ht = acct[fr][fc][reg], hg = accg[fr][fc][reg], xx = accx[fr][fc][reg];
                    float d = (z2ti + z2gi) + (e2tc[fc] + e2gc[fc])
                            - 2.0f * INV_HH * (ht + hg + xx * (1.0f / 4096.0f));
                    float lv = -100.0f * d;
                    float p = expf(lv - lsei);
                    if (fc == 0) cs0 += p; else cs1 += p;
                }
            }
        }
        cs0 += __shfl_xor(cs0, 16); cs0 += __shfl_xor(cs0, 32);
        cs1 += __shfl_xor(cs1, 16); cs1 += __shfl_xor(cs1, 32);
        if (g == 0) {
            atomicAdd(&scol[wave_c * 32 + jf], cs0);
            atomicAdd(&scol[wave_c * 32 + 16 + jf], cs1);
        }
        __syncthreads();
        if (t < 128) atomicAdd(&avgp[nj * 128 + t], scol[t]);
    }
}

// ---- merge 64 per-colblock partials per row; write pscale; NO global atomics ----
__global__ __launch_bounds__(256) void k_rowreduce(
    const float* __restrict__ pm, const float* __restrict__ pz, const float* __restrict__ ps1,
    const float* __restrict__ pdm, const float* __restrict__ pdt, const float* __restrict__ pdg,
    const int* __restrict__ pix,
    float* __restrict__ pscale, float* __restrict__ lse, int* __restrict__ idxo,
    float* __restrict__ rent, float* __restrict__ rdt, float* __restrict__ rdg,
    float* __restrict__ out)
{
    int b = blockIdx.x * 4 + (threadIdx.x >> 6);
    int l = threadIdx.x & 63;
    size_t pb = (size_t)b * 64 + l;
    float m0 = pm[pb];
    float m = m0;
#pragma unroll
    for (int s = 1; s < 64; s <<= 1) m = fmaxf(m, __shfl_xor(m, s));
    float sc = expf(m0 - m);
    float Z = pz[pb] * sc, S1 = ps1[pb] * sc;
    float dt2 = pdt[pb], dg2 = pdg[pb];
    float dmin = pdm[pb]; int dix = pix[pb];
#pragma unroll
    for (int s = 1; s < 64; s <<= 1) {
        Z += __shfl_xor(Z, s); S1 += __shfl_xor(S1, s);
        dt2 += __shfl_xor(dt2, s); dg2 += __shfl_xor(dg2, s);
        float ov = __shfl_xor(dmin, s); int oi = __shfl_xor(dix, s);
        if (ov < dmin || (ov == dmin && oi < dix)) { dmin = ov; dix = oi; }
    }
    float lseb = m + logf(Z);
    pscale[pb] = expf(m0 - lseb);
    if (l == 0) {
        lse[b] = lseb; idxo[b] = dix;
        out[O_IX + b] = (float)dix;
        rent[b] = lseb - S1 / Z;
        rdt[b] = dt2; rdg[b] = dg2;
    }
}

// ---- stored-q column sums, atomic-free: avg4[rb][n] = sum over 1024 rows ----
__global__ __launch_bounds__(256) void k_colsum(const unsigned short* __restrict__ qm,
                                                const float* __restrict__ pscale,
                                                float* __restrict__ avg4) {
    int cc = blockIdx.x, rb = blockIdx.y, t = threadIdx.x;
    int cp = t & 63, rg = t >> 6;
    float a0 = 0.f, a1 = 0.f;
    const unsigned short* qb = qm + (size_t)cc * 128 + (size_t)cp * 2;
#pragma unroll 4
    for (int rr = rg; rr < 1024; rr += 4) {
        int r = rb * 1024 + rr;
        float s = pscale[(size_t)r * 64 + cc];
        unsigned int q = *(const unsigned int*)(qb + (size_t)r * 8192);
        a0 += bf2f((unsigned short)(q & 0xffffu)) * s;
        a1 += bf2f((unsigned short)(q >> 16)) * s;
    }
    __shared__ float red[512];
    red[rg * 128 + cp * 2] = a0; red[rg * 128 + cp * 2 + 1] = a1;
    __syncthreads();
    if (rg == 0) {
        float s0 = red[cp*2]   + red[128+cp*2]   + red[256+cp*2]   + red[384+cp*2];
        float s1 = red[cp*2+1] + red[128+cp*2+1] + red[256+cp*2+1] + red[384+cp*2+1];
        avg4[(size_t)rb * 8192 + cc * 128 + cp * 2]     = s0;
        avg4[(size_t)rb * 8192 + cc * 128 + cp * 2 + 1] = s1;
    }
}

// ---- gather z_q outputs + per-row vq sums (no atomics) ----
__global__ __launch_bounds__(1024) void k_gather(
    const _Float16* __restrict__ zh, const _Float16* __restrict__ zl,
    const _Float16* __restrict__ eh, const _Float16* __restrict__ el,
    const int* __restrict__ idxi, float* __restrict__ out, float* __restrict__ gvq)
{
    int t = threadIdx.x;
    int r8 = t & 7, ck = t >> 3;
    int b = blockIdx.x * 8 + r8;
    int idx = idxi[b];
    size_t zo = tiled_off(b, ck), eo = tiled_off(idx, ck);
    f16x8 zh8 = *(const f16x8*)(zh + zo);
    f16x8 zl8 = *(const f16x8*)(zl + zo);
    f16x8 eh8 = *(const f16x8*)(eh + eo);
    f16x8 el8 = *(const f16x8*)(el + eo);
    float ss = 0.f; float oz[8], zq[8];
#pragma unroll
    for (int e = 0; e < 8; ++e) {
        float zn = ((float)zh8[e] + (float)zl8[e] * (1.0f / 4096.0f)) * (1.0f / SCL_H);
        float eq = ((float)eh8[e] + (float)el8[e] * (1.0f / 4096.0f)) * (1.0f / SCL_H);
        float df = eq - zn;
        zq[e] = eq; oz[e] = zn + df; ss += df * df;
    }
    float* dst = out + (size_t)b * 1024 + (size_t)ck * 8;
    *(float4*)dst       = make_float4(oz[0], oz[1], oz[2], oz[3]);
    *(float4*)(dst + 4) = make_float4(oz[4], oz[5], oz[6], oz[7]);
    float* tg = (ck < 64) ? (out + O_ZT + (size_t)b * 512 + (size_t)ck * 8)
                          : (out + O_ZG + (size_t)b * 512 + (size_t)(ck - 64) * 8);
    *(float4*)tg       = make_float4(zq[0], zq[1], zq[2], zq[3]);
    *(float4*)(tg + 4) = make_float4(zq[4], zq[5], zq[6], zq[7]);
    __shared__ float red[8*132];
    int ri = r8 * 132 + ck;
    red[ri] = ss; __syncthreads();
    for (int s = 64; s > 0; s >>= 1) { if (ck < s) red[ri] += red[ri + s]; __syncthreads(); }
    if (ck == 0) gvq[b] = red[ri];
}

__global__ __launch_bounds__(256) void k_finalize(const float* __restrict__ avg4,
        const float* __restrict__ rent, const float* __restrict__ rdt,
        const float* __restrict__ rdg, const float* __restrict__ gvq,
        float* __restrict__ out) {
    int t = threadIdx.x;
    float ent = 0.f, se = 0.f, dt = 0.f, dg = 0.f, vq = 0.f;
    for (int n = t; n < 8192; n += 256) {
        float a = 0.f;
#pragma unroll
        for (int k = 0; k < 8; ++k) a += avg4[(size_t)k * 8192 + n];
        a *= (1.0f / 8192.0f);
        ent -= a * logf(a + 1e-5f);
        se += rent[n]; dt += rdt[n]; dg += rdg[n]; vq += gvq[n];
    }
    __shared__ float red[256];
#define RED(x) { red[t] = x; __syncthreads(); \
    for (int s = 128; s > 0; s >>= 1) { if (t < s) red[t] += red[t + s]; __syncthreads(); } \
    x = red[0]; __syncthreads(); }
    RED(ent) RED(se) RED(dt) RED(dg) RED(vq)
#undef RED
    if (t == 0) {
        float vqm = vq * (1.0f / 8388608.0f);
        out[O_VQ]  = vqm;
        out[O_CM]  = 0.25f * vqm;
        out[O_ENT] = 0.1f * (se * (1.0f / 8192.0f) - ent);
        out[O_TD]  = dt * (1.0f / 8192.0f);
        out[O_GD]  = dg * (1.0f / 8192.0f);
    }
}

extern "C" void kernel_launch(void* const* d_in, const int* in_sizes, int n_in,
                              void* d_out, int out_size, void* d_ws, size_t ws_size,
                              hipStream_t stream) {
    const float* z  = (const float*)d_in[0];
    const float* et = (const float*)d_in[1];
    const float* eg = (const float*)d_in[2];
    float* out = (float*)d_out;
    float* ws  = (float*)d_ws;

    _Float16* zh = (_Float16*)(ws + WS_ZH);
    _Float16* zl = (_Float16*)(ws + WS_ZL);
    _Float16* eh = (_Float16*)(ws + WS_EH);
    _Float16* el = (_Float16*)(ws + WS_EL);
    float* z2t = ws + WS_Z2T;
    float* z2g = ws + WS_Z2G;
    float* e2t = ws + WS_E2T;
    float* e2g = ws + WS_E2G;
    float* pm  = ws + WS_PM;
    float* pz  = ws + WS_PZ;
    float* ps1 = ws + WS_PS1;
    float* pdm = ws + WS_PDM;
    float* pdt = ws + WS_PDT;
    float* pdg = ws + WS_PDG;
    int*   pix = (int*)(ws + WS_PIX);
    float* psc = ws + WS_PSC;
    float* lsep = ws + WS_LSE;
    int*   idxi = (int*)(ws + WS_IDX);
    float* rent = ws + WS_RENT;
    float* rdt  = ws + WS_RDT;
    float* rdg  = ws + WS_RDG;
    float* gvq  = ws + WS_GVQ;
    float* avg4 = ws + WS_AVG4;
    unsigned short* qm = (unsigned short*)(ws + WS_QM);

    bool storeq = (ws_size >= WS_STORE_END * sizeof(float));

    k_norm_z<<<1024, 1024, 0, stream>>>(z, zh, zl, z2t, z2g);
    k_norm_e<<<1024, 1024, 0, stream>>>(et, eg, eh, el, e2t, e2g);

    dim3 gg(64, 64);
    if (storeq) {
        k_gemm<1, true><<<gg, 512, 0, stream>>>(zh, zl, eh, el, z2t, z2g, e2t, e2g,
                                                pm, pz, ps1, pdm, pdt, pdg, pix, qm, lsep, avg4);
    } else {
        k_gemm<1, false><<<gg, 512, 0, stream>>>(zh, zl, eh, el, z2t, z2g, e2t, e2g,
                                                 pm, pz, ps1, pdm, pdt, pdg, pix, qm, lsep, avg4);
    }
    k_rowreduce<<<2048, 256, 0, stream>>>(pm, pz, ps1, pdm, pdt, pdg, pix,
                                          psc, lsep, idxi, rent, rdt, rdg, out);
    if (storeq) {
        k_colsum<<<dim3(64, 8), 256, 0, stream>>>(qm, psc, avg4);
    } else {
        k_zero<<<256, 256, 0, stream>>>(avg4, 65536);
        k_gemm<2, false><<<gg, 512, 0, stream>>>(zh, zl, eh, el, z2t, z2g, e2t, e2g,
                                                 pm, pz, ps1, pdm, pdt, pdg, pix, qm, lsep, avg4);
    }
    k_gather<<<1024, 1024, 0, stream>>>(zh, zl, eh, el, idxi, out, gvq);
    k_finalize<<<1, 256, 0, stream>>>(avg4, rent, rdt, rdg, gvq, out);
}